// Round 1
// baseline (281.870 us; speedup 1.0000x reference)
//
#include <hip/hip_runtime.h>
#include <hip/hip_bf16.h>

// Problem constants
#define B_  2
#define N_  2048
#define M_  2048
#define D_  512
#define H_  8
#define F_  2048
#define DH_ 64
#define ROWS 4096   // B_*N_ == B_*M_

typedef __bf16 bf16x8 __attribute__((ext_vector_type(8)));
typedef float  f32x4  __attribute__((ext_vector_type(4)));
using bf16 = __hip_bfloat16;

// ---------------------------------------------------------------------------
// LayerNorm: one wave per row of 512 f32, output bf16.
// ---------------------------------------------------------------------------
__global__ __launch_bounds__(256) void ln_kernel(
    const float* __restrict__ in, const float* __restrict__ gam,
    const float* __restrict__ bet, bf16* __restrict__ out)
{
    int wave = threadIdx.x >> 6, lane = threadIdx.x & 63;
    int row  = blockIdx.x * 4 + wave;
    const float* p = in + (size_t)row * D_ + lane * 8;
    float4 v0 = *(const float4*)p;
    float4 v1 = *(const float4*)(p + 4);
    float s  = v0.x + v0.y + v0.z + v0.w + v1.x + v1.y + v1.z + v1.w;
    float ss = v0.x*v0.x + v0.y*v0.y + v0.z*v0.z + v0.w*v0.w
             + v1.x*v1.x + v1.y*v1.y + v1.z*v1.z + v1.w*v1.w;
    for (int m = 1; m < 64; m <<= 1) {
        s  += __shfl_xor(s,  m, 64);
        ss += __shfl_xor(ss, m, 64);
    }
    float mu   = s * (1.f / D_);
    float var  = ss * (1.f / D_) - mu * mu;
    float rstd = rsqrtf(var + 1e-6f);
    int c = lane * 8;
    float4 g0 = *(const float4*)(gam + c), g1 = *(const float4*)(gam + c + 4);
    float4 b0 = *(const float4*)(bet + c), b1 = *(const float4*)(bet + c + 4);
    bf16* o = out + (size_t)row * D_ + c;
    o[0] = __float2bfloat16((v0.x - mu) * rstd * g0.x + b0.x);
    o[1] = __float2bfloat16((v0.y - mu) * rstd * g0.y + b0.y);
    o[2] = __float2bfloat16((v0.z - mu) * rstd * g0.z + b0.z);
    o[3] = __float2bfloat16((v0.w - mu) * rstd * g0.w + b0.w);
    o[4] = __float2bfloat16((v1.x - mu) * rstd * g1.x + b1.x);
    o[5] = __float2bfloat16((v1.y - mu) * rstd * g1.y + b1.y);
    o[6] = __float2bfloat16((v1.z - mu) * rstd * g1.z + b1.z);
    o[7] = __float2bfloat16((v1.w - mu) * rstd * g1.w + b1.w);
}

// ---------------------------------------------------------------------------
// Weight transpose + cast: W[K,N] f32 -> Wt[N,K] bf16.  block (32,8)
// ---------------------------------------------------------------------------
__global__ void wtrans_kernel(const float* __restrict__ W, bf16* __restrict__ Wt,
                              int K, int N)
{
    __shared__ float t[32][33];
    int tx = threadIdx.x, ty = threadIdx.y;
    int n0 = blockIdx.x * 32, k0 = blockIdx.y * 32;
    for (int j = 0; j < 32; j += 8)
        t[ty + j][tx] = W[(size_t)(k0 + ty + j) * N + n0 + tx];
    __syncthreads();
    for (int j = 0; j < 32; j += 8)
        Wt[(size_t)(n0 + ty + j) * K + k0 + tx] = __float2bfloat16(t[tx][ty + j]);
}

// ---------------------------------------------------------------------------
// V transpose per head: v[b*M+m][h*64+d] bf16 -> vt[(b*H+h)*64 + d][m] bf16
// grid (M/32, 64/32, B*H), block (32,8)
// ---------------------------------------------------------------------------
__global__ void vtrans_kernel(const bf16* __restrict__ v, bf16* __restrict__ vt)
{
    __shared__ bf16 t[32][33];
    int tx = threadIdx.x, ty = threadIdx.y;
    int bh = blockIdx.z, b = bh >> 3, h = bh & 7;
    int m0 = blockIdx.x * 32, d0 = blockIdx.y * 32;
    for (int j = 0; j < 32; j += 8)
        t[ty + j][tx] = v[(size_t)(b * M_ + m0 + ty + j) * D_ + h * DH_ + d0 + tx];
    __syncthreads();
    for (int j = 0; j < 32; j += 8)
        vt[((size_t)bh * DH_ + d0 + ty + j) * M_ + m0 + tx] = t[tx][ty + j];
}

// ---------------------------------------------------------------------------
// GEMM: C[M,N] = epilogue(A[M,K] @ Bt[N,K]^T + bias)
// A,Bt bf16 row-major. 128x128 tile, 4 waves (2x2), BK=32.
// ---------------------------------------------------------------------------
#define BM 128
#define BN 128
#define BK 32
#define LDK 40            // padded LDS row length in bf16 elems (80 B)

template<bool GELU, bool RESID, bool ROWMASK, bool OUTBF>
__global__ __launch_bounds__(256) void gemm_bt(
    const bf16* __restrict__ A, const bf16* __restrict__ Bt,
    const float* __restrict__ bias, const float* __restrict__ resid,
    const float* __restrict__ rowmask,
    bf16* __restrict__ outb, float* __restrict__ outf,
    int Mr, int Nn, int K)
{
    __shared__ bf16 As[BM * LDK];
    __shared__ bf16 Bs[BN * LDK];
    int t = threadIdx.x;
    int lane = t & 63, wave = t >> 6;
    int wm = wave >> 1, wn = wave & 1;
    int r16 = lane & 15, g = lane >> 4;
    int m0 = blockIdx.x * BM, n0 = blockIdx.y * BN;

    f32x4 acc[4][4] = {};

    for (int k0 = 0; k0 < K; k0 += BK) {
        __syncthreads();
        for (int it = 0; it < 2; ++it) {
            int c = it * 256 + t;
            int row = c >> 2, ko = (c & 3) * 8;
            uint4 dA = *(const uint4*)(A  + (size_t)(m0 + row) * K + k0 + ko);
            *(uint4*)((char*)As + row * (LDK * 2) + ko * 2) = dA;
            uint4 dB = *(const uint4*)(Bt + (size_t)(n0 + row) * K + k0 + ko);
            *(uint4*)((char*)Bs + row * (LDK * 2) + ko * 2) = dB;
        }
        __syncthreads();
        bf16x8 af[4], bfr[4];
        for (int i = 0; i < 4; ++i)
            af[i]  = *(const bf16x8*)((char*)As + (wm * 64 + i * 16 + r16) * (LDK * 2) + g * 16);
        for (int i = 0; i < 4; ++i)
            bfr[i] = *(const bf16x8*)((char*)Bs + (wn * 64 + i * 16 + r16) * (LDK * 2) + g * 16);
        for (int i = 0; i < 4; ++i)
            for (int j = 0; j < 4; ++j)
                acc[i][j] = __builtin_amdgcn_mfma_f32_16x16x32_bf16(af[i], bfr[j], acc[i][j], 0, 0, 0);
    }

    for (int i = 0; i < 4; ++i) {
        int rb = m0 + wm * 64 + i * 16 + g * 4;
        for (int j = 0; j < 4; ++j) {
            int cb = n0 + wn * 64 + j * 16 + r16;
            float bia = bias[cb];
            for (int e = 0; e < 4; ++e) {
                int rr = rb + e;
                float val = acc[i][j][e] + bia;
                if (GELU)    val = 0.5f * val * (1.f + erff(val * 0.70710678118654752f));
                if (RESID)   val += resid[(size_t)rr * Nn + cb];
                if (ROWMASK) val *= rowmask[rr];
                if (OUTBF)   outb[(size_t)rr * Nn + cb] = __float2bfloat16(val);
                else         outf[(size_t)rr * Nn + cb] = val;
            }
        }
    }
}

// ---------------------------------------------------------------------------
// Flash attention: grid (N/64, B*H), block 256 (4 waves, 16 q-rows each).
// q,k: bf16 [B*rows, D]; vt: bf16 [B*H, 64, M]; ctx out bf16 [B*N, D].
// ---------------------------------------------------------------------------
__global__ __launch_bounds__(256) void attn_kernel(
    const bf16* __restrict__ q, const bf16* __restrict__ kk,
    const bf16* __restrict__ vt, bf16* __restrict__ ctx)
{
    int bh = blockIdx.y, b = bh >> 3, h = bh & 7;
    int n0 = blockIdx.x * 64;
    int t = threadIdx.x, lane = t & 63, wave = t >> 6;
    int r16 = lane & 15, g = lane >> 4;

    __shared__ bf16 plds[4][16][72];   // per-wave P tile (pad 64->72)

    int qrow = b * N_ + n0 + wave * 16 + r16;
    bf16x8 qf[2];
    for (int ks = 0; ks < 2; ++ks)
        qf[ks] = *(const bf16x8*)(q + (size_t)qrow * D_ + h * DH_ + ks * 32 + g * 8);

    f32x4 cacc[4] = {};
    float mrow[4], lrow[4];
    for (int e = 0; e < 4; ++e) { mrow[e] = -1e30f; lrow[e] = 0.f; }

    const bf16* kbase = kk + (size_t)b * M_ * D_ + h * DH_;
    const bf16* vtb   = vt + (size_t)bh * DH_ * M_;

    for (int m0 = 0; m0 < M_; m0 += 64) {
        f32x4 sacc[4] = {};
        for (int nf = 0; nf < 4; ++nf) {
            int key = m0 + nf * 16 + r16;
            for (int ks = 0; ks < 2; ++ks) {
                bf16x8 kf = *(const bf16x8*)(kbase + (size_t)key * D_ + ks * 32 + g * 8);
                sacc[nf] = __builtin_amdgcn_mfma_f32_16x16x32_bf16(qf[ks], kf, sacc[nf], 0, 0, 0);
            }
        }
        for (int nf = 0; nf < 4; ++nf)
            for (int e = 0; e < 4; ++e) sacc[nf][e] *= 0.125f;

        float mnew[4], scl[4];
        for (int e = 0; e < 4; ++e) {
            float mt = fmaxf(fmaxf(sacc[0][e], sacc[1][e]), fmaxf(sacc[2][e], sacc[3][e]));
            for (int m = 1; m < 16; m <<= 1) mt = fmaxf(mt, __shfl_xor(mt, m, 64));
            mnew[e] = fmaxf(mrow[e], mt);
            scl[e]  = __expf(mrow[e] - mnew[e]);
            mrow[e] = mnew[e];
        }
        float psum[4] = {0.f, 0.f, 0.f, 0.f};
        for (int nf = 0; nf < 4; ++nf)
            for (int e = 0; e < 4; ++e) {
                float p = __expf(sacc[nf][e] - mnew[e]);
                psum[e] += p;
                plds[wave][4 * g + e][nf * 16 + r16] = __float2bfloat16(p);
            }
        for (int e = 0; e < 4; ++e) {
            float ps = psum[e];
            for (int m = 1; m < 16; m <<= 1) ps += __shfl_xor(ps, m, 64);
            lrow[e] = lrow[e] * scl[e] + ps;
            for (int df = 0; df < 4; ++df) cacc[df][e] *= scl[e];
        }
        for (int ks = 0; ks < 2; ++ks) {
            bf16x8 pf = *(const bf16x8*)((char*)&plds[wave][0][0] + r16 * 144 + ks * 64 + g * 16);
            for (int df = 0; df < 4; ++df) {
                bf16x8 vf = *(const bf16x8*)(vtb + (size_t)(df * 16 + r16) * M_ + m0 + ks * 32 + g * 8);
                cacc[df] = __builtin_amdgcn_mfma_f32_16x16x32_bf16(pf, vf, cacc[df], 0, 0, 0);
            }
        }
    }

    for (int df = 0; df < 4; ++df)
        for (int e = 0; e < 4; ++e) {
            int row = b * N_ + n0 + wave * 16 + 4 * g + e;
            ctx[(size_t)row * D_ + h * DH_ + df * 16 + r16] =
                __float2bfloat16(cacc[df][e] / lrow[e]);
        }
}

// ---------------------------------------------------------------------------
extern "C" void kernel_launch(void* const* d_in, const int* in_sizes, int n_in,
                              void* d_out, int out_size, void* d_ws, size_t ws_size,
                              hipStream_t stream)
{
    const float* x      = (const float*)d_in[0];
    const float* y      = (const float*)d_in[1];
    const float* mask_x = (const float*)d_in[2];
    const float* mask_y = (const float*)d_in[3];
    const float* Wq = (const float*)d_in[4];  const float* bq = (const float*)d_in[5];
    const float* Wk = (const float*)d_in[6];  const float* bk = (const float*)d_in[7];
    const float* Wv = (const float*)d_in[8];  const float* bv = (const float*)d_in[9];
    const float* Wo = (const float*)d_in[10]; const float* bo = (const float*)d_in[11];
    const float* W1 = (const float*)d_in[12]; const float* b1 = (const float*)d_in[13];
    const float* W2 = (const float*)d_in[14]; const float* b2 = (const float*)d_in[15];
    const float* ln1g = (const float*)d_in[16]; const float* ln1b = (const float*)d_in[17];
    const float* ln2g = (const float*)d_in[18]; const float* ln2b = (const float*)d_in[19];

    char* ws = (char*)d_ws;
    const size_t SZA = (size_t)ROWS * D_ * 2;     // 4 MiB bf16 activation
    bf16* xn   = (bf16*)ws;            ws += SZA;
    bf16* yn   = (bf16*)ws;            ws += SZA;
    bf16* qb   = (bf16*)ws;            ws += SZA;
    bf16* kb   = (bf16*)ws;            ws += SZA;
    bf16* vb   = (bf16*)ws;            ws += SZA;
    bf16* vtb  = (bf16*)ws;            ws += SZA;
    bf16* ctxb = (bf16*)ws;            ws += SZA;
    bf16* xn2  = (bf16*)ws;            ws += SZA;
    bf16* hff  = (bf16*)ws;            ws += (size_t)ROWS * F_ * 2;
    float* x1  = (float*)ws;           ws += (size_t)ROWS * D_ * 4;
    bf16* Wqt = (bf16*)ws;             ws += (size_t)D_ * D_ * 2;
    bf16* Wkt = (bf16*)ws;             ws += (size_t)D_ * D_ * 2;
    bf16* Wvt = (bf16*)ws;             ws += (size_t)D_ * D_ * 2;
    bf16* Wot = (bf16*)ws;             ws += (size_t)D_ * D_ * 2;
    bf16* W1t = (bf16*)ws;             ws += (size_t)D_ * F_ * 2;
    bf16* W2t = (bf16*)ws;             ws += (size_t)F_ * D_ * 2;

    dim3 tb(32, 8);
    wtrans_kernel<<<dim3(D_ / 32, D_ / 32), tb, 0, stream>>>(Wq, Wqt, D_, D_);
    wtrans_kernel<<<dim3(D_ / 32, D_ / 32), tb, 0, stream>>>(Wk, Wkt, D_, D_);
    wtrans_kernel<<<dim3(D_ / 32, D_ / 32), tb, 0, stream>>>(Wv, Wvt, D_, D_);
    wtrans_kernel<<<dim3(D_ / 32, D_ / 32), tb, 0, stream>>>(Wo, Wot, D_, D_);
    wtrans_kernel<<<dim3(F_ / 32, D_ / 32), tb, 0, stream>>>(W1, W1t, D_, F_);
    wtrans_kernel<<<dim3(D_ / 32, F_ / 32), tb, 0, stream>>>(W2, W2t, F_, D_);

    ln_kernel<<<ROWS / 4, 256, 0, stream>>>(x, ln1g, ln1b, xn);
    ln_kernel<<<ROWS / 4, 256, 0, stream>>>(y, ln1g, ln1b, yn);

    // Q/K/V projections (bias + row mask, bf16 out)
    gemm_bt<false, false, true, true><<<dim3(ROWS / BM, D_ / BN), 256, 0, stream>>>(
        xn, Wqt, bq, nullptr, mask_x, qb, nullptr, ROWS, D_, D_);
    gemm_bt<false, false, true, true><<<dim3(ROWS / BM, D_ / BN), 256, 0, stream>>>(
        yn, Wkt, bk, nullptr, mask_y, kb, nullptr, ROWS, D_, D_);
    gemm_bt<false, false, true, true><<<dim3(ROWS / BM, D_ / BN), 256, 0, stream>>>(
        yn, Wvt, bv, nullptr, mask_y, vb, nullptr, ROWS, D_, D_);

    vtrans_kernel<<<dim3(M_ / 32, DH_ / 32, B_ * H_), tb, 0, stream>>>(vb, vtb);

    attn_kernel<<<dim3(N_ / 64, B_ * H_), 256, 0, stream>>>(qb, kb, vtb, ctxb);

    // out-proj + residual(x) -> x1 (f32)
    gemm_bt<false, true, false, false><<<dim3(ROWS / BM, D_ / BN), 256, 0, stream>>>(
        ctxb, Wot, bo, x, nullptr, nullptr, x1, ROWS, D_, D_);

    ln_kernel<<<ROWS / 4, 256, 0, stream>>>(x1, ln2g, ln2b, xn2);

    // MLP1 + GELU -> hff (bf16)
    gemm_bt<true, false, false, true><<<dim3(ROWS / BM, F_ / BN), 256, 0, stream>>>(
        xn2, W1t, b1, nullptr, nullptr, hff, nullptr, ROWS, F_, D_);

    // MLP2 + residual(x1) -> d_out (f32)
    gemm_bt<false, true, false, false><<<dim3(ROWS / BM, D_ / BN), 256, 0, stream>>>(
        hff, W2t, b2, x1, nullptr, nullptr, (float*)d_out, ROWS, D_, F_);
}

// Round 4
// 278.419 us; speedup vs baseline: 1.0124x; 1.0124x over previous
//
#include <hip/hip_runtime.h>
#include <hip/hip_bf16.h>

// Problem constants
#define B_  2
#define N_  2048
#define M_  2048
#define D_  512
#define H_  8
#define F_  2048
#define DH_ 64
#define ROWS 4096   // B_*N_ == B_*M_

#define SPLIT 2
#define KV_PER (M_ / SPLIT)   // 1024
#define NT (KV_PER / 64)      // 16 tiles of 64 keys

typedef __bf16 bf16x8 __attribute__((ext_vector_type(8)));
typedef float  f32x4  __attribute__((ext_vector_type(4)));
using bf16 = __hip_bfloat16;

// ---------------------------------------------------------------------------
// LayerNorm: one wave per row of 512 f32, output bf16.
// ---------------------------------------------------------------------------
__global__ __launch_bounds__(256) void ln_kernel(
    const float* __restrict__ in, const float* __restrict__ gam,
    const float* __restrict__ bet, bf16* __restrict__ out)
{
    int wave = threadIdx.x >> 6, lane = threadIdx.x & 63;
    int row  = blockIdx.x * 4 + wave;
    const float* p = in + (size_t)row * D_ + lane * 8;
    float4 v0 = *(const float4*)p;
    float4 v1 = *(const float4*)(p + 4);
    float s  = v0.x + v0.y + v0.z + v0.w + v1.x + v1.y + v1.z + v1.w;
    float ss = v0.x*v0.x + v0.y*v0.y + v0.z*v0.z + v0.w*v0.w
             + v1.x*v1.x + v1.y*v1.y + v1.z*v1.z + v1.w*v1.w;
    for (int m = 1; m < 64; m <<= 1) {
        s  += __shfl_xor(s,  m, 64);
        ss += __shfl_xor(ss, m, 64);
    }
    float mu   = s * (1.f / D_);
    float var  = ss * (1.f / D_) - mu * mu;
    float rstd = rsqrtf(var + 1e-6f);
    int c = lane * 8;
    float4 g0 = *(const float4*)(gam + c), g1 = *(const float4*)(gam + c + 4);
    float4 b0 = *(const float4*)(bet + c), b1 = *(const float4*)(bet + c + 4);
    bf16* o = out + (size_t)row * D_ + c;
    o[0] = __float2bfloat16((v0.x - mu) * rstd * g0.x + b0.x);
    o[1] = __float2bfloat16((v0.y - mu) * rstd * g0.y + b0.y);
    o[2] = __float2bfloat16((v0.z - mu) * rstd * g0.z + b0.z);
    o[3] = __float2bfloat16((v0.w - mu) * rstd * g0.w + b0.w);
    o[4] = __float2bfloat16((v1.x - mu) * rstd * g1.x + b1.x);
    o[5] = __float2bfloat16((v1.y - mu) * rstd * g1.y + b1.y);
    o[6] = __float2bfloat16((v1.z - mu) * rstd * g1.z + b1.z);
    o[7] = __float2bfloat16((v1.w - mu) * rstd * g1.w + b1.w);
}

// ---------------------------------------------------------------------------
// Weight transpose + cast: W[K,N] f32 -> Wt[N,K] bf16.  block (32,8)
// ---------------------------------------------------------------------------
__global__ void wtrans_kernel(const float* __restrict__ W, bf16* __restrict__ Wt,
                              int K, int N)
{
    __shared__ float t[32][33];
    int tx = threadIdx.x, ty = threadIdx.y;
    int n0 = blockIdx.x * 32, k0 = blockIdx.y * 32;
    for (int j = 0; j < 32; j += 8)
        t[ty + j][tx] = W[(size_t)(k0 + ty + j) * N + n0 + tx];
    __syncthreads();
    for (int j = 0; j < 32; j += 8)
        Wt[(size_t)(n0 + ty + j) * K + k0 + tx] = __float2bfloat16(t[tx][ty + j]);
}

// ---------------------------------------------------------------------------
// V transpose per head: v[b*M+m][h*64+d] bf16 -> vt[(b*H+h)*64 + d][m] bf16
// ---------------------------------------------------------------------------
__global__ void vtrans_kernel(const bf16* __restrict__ v, bf16* __restrict__ vt)
{
    __shared__ bf16 t[32][33];
    int tx = threadIdx.x, ty = threadIdx.y;
    int bh = blockIdx.z, b = bh >> 3, h = bh & 7;
    int m0 = blockIdx.x * 32, d0 = blockIdx.y * 32;
    for (int j = 0; j < 32; j += 8)
        t[ty + j][tx] = v[(size_t)(b * M_ + m0 + ty + j) * D_ + h * DH_ + d0 + tx];
    __syncthreads();
    for (int j = 0; j < 32; j += 8)
        vt[((size_t)bh * DH_ + d0 + ty + j) * M_ + m0 + tx] = t[tx][ty + j];
}

// ---------------------------------------------------------------------------
// Generic GEMM: C[M,N] = epilogue(A[M,K] @ Bt[N,K]^T + bias)
// 128x128 tile, 4 waves (2x2), BK=32.
// ---------------------------------------------------------------------------
#define BM 128
#define BN 128
#define BK 32
#define LDK 40            // padded LDS row length in bf16 elems (80 B)

#define GEMM_BODY(Aptr, Btptr, KK, EPILOGUE)                                         \
    __shared__ bf16 As[BM * LDK];                                                    \
    __shared__ bf16 Bs[BN * LDK];                                                    \
    int t = threadIdx.x;                                                             \
    int lane = t & 63, wave = t >> 6;                                                \
    int wm = wave >> 1, wn = wave & 1;                                               \
    int r16 = lane & 15, g = lane >> 4;                                              \
    int m0 = blockIdx.x * BM, n0 = blockIdx.y * BN;                                  \
    f32x4 acc[4][4] = {};                                                            \
    for (int k0 = 0; k0 < (KK); k0 += BK) {                                          \
        __syncthreads();                                                             \
        for (int it = 0; it < 2; ++it) {                                             \
            int c = it * 256 + t;                                                    \
            int row = c >> 2, ko = (c & 3) * 8;                                      \
            uint4 dA = *(const uint4*)((Aptr)  + (size_t)(m0 + row) * (KK) + k0 + ko); \
            *(uint4*)((char*)As + row * (LDK * 2) + ko * 2) = dA;                    \
            uint4 dB = *(const uint4*)((Btptr) + (size_t)(n0 + row) * (KK) + k0 + ko); \
            *(uint4*)((char*)Bs + row * (LDK * 2) + ko * 2) = dB;                    \
        }                                                                            \
        __syncthreads();                                                             \
        bf16x8 af[4], bfr[4];                                                        \
        for (int i = 0; i < 4; ++i)                                                  \
            af[i]  = *(const bf16x8*)((char*)As + (wm * 64 + i * 16 + r16) * (LDK * 2) + g * 16); \
        for (int i = 0; i < 4; ++i)                                                  \
            bfr[i] = *(const bf16x8*)((char*)Bs + (wn * 64 + i * 16 + r16) * (LDK * 2) + g * 16); \
        for (int i = 0; i < 4; ++i)                                                  \
            for (int j = 0; j < 4; ++j)                                              \
                acc[i][j] = __builtin_amdgcn_mfma_f32_16x16x32_bf16(af[i], bfr[j], acc[i][j], 0, 0, 0); \
    }                                                                                \
    for (int i = 0; i < 4; ++i) {                                                    \
        int rb = m0 + wm * 64 + i * 16 + g * 4;                                      \
        for (int j = 0; j < 4; ++j) {                                                \
            int cb = n0 + wn * 64 + j * 16 + r16;                                    \
            float bia = bias[cb];                                                    \
            for (int e = 0; e < 4; ++e) {                                            \
                int rr = rb + e;                                                     \
                float val = acc[i][j][e] + bia;                                      \
                EPILOGUE                                                             \
            }                                                                        \
        }                                                                            \
    }

template<bool GELU, bool RESID, bool ROWMASK, bool OUTBF>
__global__ __launch_bounds__(256) void gemm_bt(
    const bf16* __restrict__ A, const bf16* __restrict__ Bt,
    const float* __restrict__ bias, const float* __restrict__ resid,
    const float* __restrict__ rowmask,
    bf16* __restrict__ outb, float* __restrict__ outf,
    int Mr, int Nn, int K)
{
    GEMM_BODY(A, Bt, K,
        if (GELU)    val = 0.5f * val * (1.f + erff(val * 0.70710678118654752f));
        if (RESID)   val += resid[(size_t)rr * Nn + cb];
        if (ROWMASK) val *= rowmask[rr];
        if (OUTBF)   outb[(size_t)rr * Nn + cb] = __float2bfloat16(val);
        else         outf[(size_t)rr * Nn + cb] = val;
    )
}

// Batched Q/K/V projection: blockIdx.z selects Q, K, or V. One launch.
__global__ __launch_bounds__(256) void gemm_qkv(
    const bf16* __restrict__ xn, const bf16* __restrict__ yn,
    const bf16* __restrict__ Wqt, const bf16* __restrict__ Wkt, const bf16* __restrict__ Wvt,
    const float* __restrict__ bq, const float* __restrict__ bk, const float* __restrict__ bv,
    const float* __restrict__ mask_x, const float* __restrict__ mask_y,
    bf16* __restrict__ qb, bf16* __restrict__ kb, bf16* __restrict__ vb)
{
    int z = blockIdx.z;
    const bf16* A        = z == 0 ? xn : yn;
    const bf16* Bt       = z == 0 ? Wqt : (z == 1 ? Wkt : Wvt);
    const float* bias    = z == 0 ? bq  : (z == 1 ? bk  : bv);
    const float* rowmask = z == 0 ? mask_x : mask_y;
    bf16* outb           = z == 0 ? qb  : (z == 1 ? kb  : vb);
    GEMM_BODY(A, Bt, D_,
        val *= rowmask[rr];
        outb[(size_t)rr * D_ + cb] = __float2bfloat16(val);
    )
}

// ---------------------------------------------------------------------------
// Flash attention, split-M: grid (N/64, B*H, SPLIT), block 256 (4 waves,
// 16 q-rows each, 1024 keys per block). Register double-buffered K/V tiles.
// Outputs unnormalized numerator (f32) + per-row (m, l).
// ---------------------------------------------------------------------------
__global__ __launch_bounds__(256, 2) void attn_kernel(
    const bf16* __restrict__ q, const bf16* __restrict__ kk,
    const bf16* __restrict__ vt, float* __restrict__ num,
    float* __restrict__ ml)
{
    int bh = blockIdx.y, b = bh >> 3, h = bh & 7;
    int n0 = blockIdx.x * 64;
    int sp = blockIdx.z;
    int t = threadIdx.x, lane = t & 63, wave = t >> 6;
    int r16 = lane & 15, g = lane >> 4;

    __shared__ bf16 plds[4][16][72];   // per-wave P tile (pad 64->72)

    // Q fragment, pre-scaled by 1/sqrt(dh) = 0.125 (exact in bf16)
    int qrow = b * N_ + n0 + wave * 16 + r16;
    bf16x8 qf[2];
    for (int ks = 0; ks < 2; ++ks) {
        bf16x8 qv = *(const bf16x8*)(q + (size_t)qrow * D_ + h * DH_ + ks * 32 + g * 8);
        for (int j = 0; j < 8; ++j) qv[j] = (__bf16)((float)qv[j] * 0.125f);
        qf[ks] = qv;
    }

    f32x4 cacc[4] = {};
    float mrow[4], lrow[4];
    for (int e = 0; e < 4; ++e) { mrow[e] = -1e30f; lrow[e] = 0.f; }

    const bf16* kbase = kk + (size_t)(b * M_ + sp * KV_PER) * D_ + h * DH_;
    const bf16* vtb   = vt + (size_t)bh * DH_ * M_ + sp * KV_PER;

#define LOADK(dst, tt) do { int _t = (tt);                                          \
    for (int nf = 0; nf < 4; ++nf)                                                  \
        for (int ks = 0; ks < 2; ++ks)                                              \
            dst[nf * 2 + ks] = *(const bf16x8*)(kbase                               \
                + (size_t)(_t * 64 + nf * 16 + r16) * D_ + ks * 32 + g * 8);        \
    } while (0)

#define LOADV(dst, tt) do { int _t = (tt);                                          \
    for (int df = 0; df < 4; ++df)                                                  \
        for (int ks = 0; ks < 2; ++ks)                                              \
            dst[df * 2 + ks] = *(const bf16x8*)(vtb                                 \
                + (size_t)(df * 16 + r16) * M_ + _t * 64 + ks * 32 + g * 8);        \
    } while (0)

#define COMPUTE(kr, vr) do {                                                        \
    f32x4 sacc[4] = {};                                                             \
    for (int nf = 0; nf < 4; ++nf)                                                  \
        for (int ks = 0; ks < 2; ++ks)                                              \
            sacc[nf] = __builtin_amdgcn_mfma_f32_16x16x32_bf16(qf[ks], kr[nf * 2 + ks], sacc[nf], 0, 0, 0); \
    float mnew[4], scl[4];                                                          \
    for (int e = 0; e < 4; ++e) {                                                   \
        float mt = fmaxf(fmaxf(sacc[0][e], sacc[1][e]), fmaxf(sacc[2][e], sacc[3][e])); \
        for (int mm = 1; mm < 16; mm <<= 1) mt = fmaxf(mt, __shfl_xor(mt, mm, 64)); \
        mnew[e] = fmaxf(mrow[e], mt);                                               \
        scl[e]  = __expf(mrow[e] - mnew[e]);                                        \
        mrow[e] = mnew[e];                                                          \
    }                                                                               \
    float psum[4] = {0.f, 0.f, 0.f, 0.f};                                           \
    for (int nf = 0; nf < 4; ++nf)                                                  \
        for (int e = 0; e < 4; ++e) {                                               \
            float p = __expf(sacc[nf][e] - mnew[e]);                                \
            psum[e] += p;                                                           \
            plds[wave][4 * g + e][nf * 16 + r16] = __float2bfloat16(p);             \
        }                                                                           \
    for (int e = 0; e < 4; ++e) {                                                   \
        float ps = psum[e];                                                         \
        for (int mm = 1; mm < 16; mm <<= 1) ps += __shfl_xor(ps, mm, 64);           \
        lrow[e] = lrow[e] * scl[e] + ps;                                            \
        for (int df = 0; df < 4; ++df) cacc[df][e] *= scl[e];                       \
    }                                                                               \
    for (int ks = 0; ks < 2; ++ks) {                                                \
        bf16x8 pf = *(const bf16x8*)((char*)&plds[wave][0][0] + r16 * 144 + ks * 64 + g * 16); \
        for (int df = 0; df < 4; ++df)                                              \
            cacc[df] = __builtin_amdgcn_mfma_f32_16x16x32_bf16(pf, vr[df * 2 + ks], cacc[df], 0, 0, 0); \
    }                                                                               \
    } while (0)

    bf16x8 kA[8], vA[8], kB[8], vB[8];
    LOADK(kA, 0); LOADV(vA, 0);
    for (int tt = 0; tt < NT; tt += 2) {
        LOADK(kB, tt + 1); LOADV(vB, tt + 1);
        COMPUTE(kA, vA);
        int nx2 = (tt + 2 < NT) ? tt + 2 : 0;   // dummy refetch on last iter
        LOADK(kA, nx2); LOADV(vA, nx2);
        COMPUTE(kB, vB);
    }

    // unnormalized numerator out (f32) + (m, l) per row
    for (int df = 0; df < 4; ++df)
        for (int e = 0; e < 4; ++e) {
            int grow = b * N_ + n0 + wave * 16 + 4 * g + e;
            num[(size_t)sp * ROWS * D_ + (size_t)grow * D_ + h * DH_ + df * 16 + r16] = cacc[df][e];
        }
    if (r16 == 0) {
        for (int e = 0; e < 4; ++e) {
            size_t off = ((size_t)(sp * (B_ * H_) + bh) * N_ + (n0 + wave * 16 + 4 * g + e)) * 2;
            ml[off] = mrow[e]; ml[off + 1] = lrow[e];
        }
    }
#undef LOADK
#undef LOADV
#undef COMPUTE
}

// Combine the SPLIT partials -> bf16 ctx
__global__ __launch_bounds__(256) void attn_combine(
    const float* __restrict__ num, const float* __restrict__ ml,
    bf16* __restrict__ ctx)
{
    int idx = blockIdx.x * 256 + threadIdx.x;
    int row = idx >> 7;              // 128 four-col chunks per row
    int c4  = (idx & 127) << 2;
    int b = row >> 11, n = row & (N_ - 1);
    int h = c4 >> 6;
    int bh = (b << 3) + h;
    const float* ml0 = ml + ((size_t)bh * N_ + n) * 2;
    const float* ml1 = ml + ((size_t)(B_ * H_ + bh) * N_ + n) * 2;
    float m0 = ml0[0], l0 = ml0[1];
    float m1 = ml1[0], l1 = ml1[1];
    float mx = fmaxf(m0, m1);
    float w0 = __expf(m0 - mx), w1 = __expf(m1 - mx);
    float inv = 1.f / (w0 * l0 + w1 * l1);
    float4 a  = *(const float4*)(num + (size_t)row * D_ + c4);
    float4 bb = *(const float4*)(num + (size_t)ROWS * D_ + (size_t)row * D_ + c4);
    bf16* o = ctx + (size_t)row * D_ + c4;
    o[0] = __float2bfloat16((w0 * a.x + w1 * bb.x) * inv);
    o[1] = __float2bfloat16((w0 * a.y + w1 * bb.y) * inv);
    o[2] = __float2bfloat16((w0 * a.z + w1 * bb.z) * inv);
    o[3] = __float2bfloat16((w0 * a.w + w1 * bb.w) * inv);
}

// ---------------------------------------------------------------------------
extern "C" void kernel_launch(void* const* d_in, const int* in_sizes, int n_in,
                              void* d_out, int out_size, void* d_ws, size_t ws_size,
                              hipStream_t stream)
{
    const float* x      = (const float*)d_in[0];
    const float* y      = (const float*)d_in[1];
    const float* mask_x = (const float*)d_in[2];
    const float* mask_y = (const float*)d_in[3];
    const float* Wq = (const float*)d_in[4];  const float* bq = (const float*)d_in[5];
    const float* Wk = (const float*)d_in[6];  const float* bk = (const float*)d_in[7];
    const float* Wv = (const float*)d_in[8];  const float* bv = (const float*)d_in[9];
    const float* Wo = (const float*)d_in[10]; const float* bo = (const float*)d_in[11];
    const float* W1 = (const float*)d_in[12]; const float* b1 = (const float*)d_in[13];
    const float* W2 = (const float*)d_in[14]; const float* b2 = (const float*)d_in[15];
    const float* ln1g = (const float*)d_in[16]; const float* ln1b = (const float*)d_in[17];
    const float* ln2g = (const float*)d_in[18]; const float* ln2b = (const float*)d_in[19];

    char* ws = (char*)d_ws;
    const size_t SZA = (size_t)ROWS * D_ * 2;     // 4 MiB bf16 activation
    bf16* xn   = (bf16*)ws;            ws += SZA;
    bf16* yn   = (bf16*)ws;            ws += SZA;
    bf16* qb   = (bf16*)ws;            ws += SZA;
    bf16* kb   = (bf16*)ws;            ws += SZA;
    bf16* vb   = (bf16*)ws;            ws += SZA;
    bf16* vtb  = (bf16*)ws;            ws += SZA;
    bf16* ctxb = (bf16*)ws;            ws += SZA;
    bf16* xn2  = (bf16*)ws;            ws += SZA;
    bf16* hff  = (bf16*)ws;            ws += (size_t)ROWS * F_ * 2;
    float* x1  = (float*)ws;           ws += (size_t)ROWS * D_ * 4;
    bf16* Wqt = (bf16*)ws;             ws += (size_t)D_ * D_ * 2;
    bf16* Wkt = (bf16*)ws;             ws += (size_t)D_ * D_ * 2;
    bf16* Wvt = (bf16*)ws;             ws += (size_t)D_ * D_ * 2;
    bf16* Wot = (bf16*)ws;             ws += (size_t)D_ * D_ * 2;
    bf16* W1t = (bf16*)ws;             ws += (size_t)D_ * F_ * 2;
    bf16* W2t = (bf16*)ws;             ws += (size_t)F_ * D_ * 2;
    float* num = (float*)ws;           ws += (size_t)SPLIT * ROWS * D_ * 4;
    float* mlb = (float*)ws;           ws += (size_t)SPLIT * B_ * H_ * N_ * 2 * 4;

    dim3 tb(32, 8);
    wtrans_kernel<<<dim3(D_ / 32, D_ / 32), tb, 0, stream>>>(Wq, Wqt, D_, D_);
    wtrans_kernel<<<dim3(D_ / 32, D_ / 32), tb, 0, stream>>>(Wk, Wkt, D_, D_);
    wtrans_kernel<<<dim3(D_ / 32, D_ / 32), tb, 0, stream>>>(Wv, Wvt, D_, D_);
    wtrans_kernel<<<dim3(D_ / 32, D_ / 32), tb, 0, stream>>>(Wo, Wot, D_, D_);
    wtrans_kernel<<<dim3(F_ / 32, D_ / 32), tb, 0, stream>>>(W1, W1t, D_, F_);
    wtrans_kernel<<<dim3(D_ / 32, F_ / 32), tb, 0, stream>>>(W2, W2t, F_, D_);

    ln_kernel<<<ROWS / 4, 256, 0, stream>>>(x, ln1g, ln1b, xn);
    ln_kernel<<<ROWS / 4, 256, 0, stream>>>(y, ln1g, ln1b, yn);

    // Q/K/V projections, one batched launch (z = 0,1,2)
    gemm_qkv<<<dim3(ROWS / BM, D_ / BN, 3), 256, 0, stream>>>(
        xn, yn, Wqt, Wkt, Wvt, bq, bk, bv, mask_x, mask_y, qb, kb, vb);

    vtrans_kernel<<<dim3(M_ / 32, DH_ / 32, B_ * H_), tb, 0, stream>>>(vb, vtb);

    attn_kernel<<<dim3(N_ / 64, B_ * H_, SPLIT), 256, 0, stream>>>(qb, kb, vtb, num, mlb);
    attn_combine<<<(ROWS * D_ / 4) / 256, 256, 0, stream>>>(num, mlb, ctxb);

    // out-proj + residual(x) -> x1 (f32)
    gemm_bt<false, true, false, false><<<dim3(ROWS / BM, D_ / BN), 256, 0, stream>>>(
        ctxb, Wot, bo, x, nullptr, nullptr, x1, ROWS, D_, D_);

    ln_kernel<<<ROWS / 4, 256, 0, stream>>>(x1, ln2g, ln2b, xn2);

    // MLP1 + GELU -> hff (bf16)
    gemm_bt<true, false, false, true><<<dim3(ROWS / BM, F_ / BN), 256, 0, stream>>>(
        xn2, W1t, b1, nullptr, nullptr, hff, nullptr, ROWS, F_, D_);

    // MLP2 + residual(x1) -> d_out (f32)
    gemm_bt<false, true, false, false><<<dim3(ROWS / BM, D_ / BN), 256, 0, stream>>>(
        hff, W2t, b2, x1, nullptr, nullptr, (float*)d_out, ROWS, D_, F_);
}

// Round 5
// 248.620 us; speedup vs baseline: 1.1337x; 1.1199x over previous
//
#include <hip/hip_runtime.h>
#include <hip/hip_bf16.h>

// Problem constants
#define B_  2
#define N_  2048
#define M_  2048
#define D_  512
#define H_  8
#define F_  2048
#define DH_ 64
#define ROWS 4096   // B_*N_ == B_*M_

#define SPLIT 2
#define KV_PER (M_ / SPLIT)   // 1024
#define NT (KV_PER / 64)      // 16 tiles of 64 keys

typedef __bf16 bf16x8 __attribute__((ext_vector_type(8)));
typedef __bf16 bf16x4v __attribute__((ext_vector_type(4)));
typedef float  f32x4  __attribute__((ext_vector_type(4)));
using bf16 = __hip_bfloat16;

// ---------------------------------------------------------------------------
// LayerNorm: one wave per row of 512 f32, output bf16.
// ---------------------------------------------------------------------------
__global__ __launch_bounds__(256) void ln_kernel(
    const float* __restrict__ in, const float* __restrict__ gam,
    const float* __restrict__ bet, bf16* __restrict__ out)
{
    int wave = threadIdx.x >> 6, lane = threadIdx.x & 63;
    int row  = blockIdx.x * 4 + wave;
    const float* p = in + (size_t)row * D_ + lane * 8;
    float4 v0 = *(const float4*)p;
    float4 v1 = *(const float4*)(p + 4);
    float s  = v0.x + v0.y + v0.z + v0.w + v1.x + v1.y + v1.z + v1.w;
    float ss = v0.x*v0.x + v0.y*v0.y + v0.z*v0.z + v0.w*v0.w
             + v1.x*v1.x + v1.y*v1.y + v1.z*v1.z + v1.w*v1.w;
    for (int m = 1; m < 64; m <<= 1) {
        s  += __shfl_xor(s,  m, 64);
        ss += __shfl_xor(ss, m, 64);
    }
    float mu   = s * (1.f / D_);
    float var  = ss * (1.f / D_) - mu * mu;
    float rstd = rsqrtf(var + 1e-6f);
    int c = lane * 8;
    float4 g0 = *(const float4*)(gam + c), g1 = *(const float4*)(gam + c + 4);
    float4 b0 = *(const float4*)(bet + c), b1 = *(const float4*)(bet + c + 4);
    bf16* o = out + (size_t)row * D_ + c;
    o[0] = __float2bfloat16((v0.x - mu) * rstd * g0.x + b0.x);
    o[1] = __float2bfloat16((v0.y - mu) * rstd * g0.y + b0.y);
    o[2] = __float2bfloat16((v0.z - mu) * rstd * g0.z + b0.z);
    o[3] = __float2bfloat16((v0.w - mu) * rstd * g0.w + b0.w);
    o[4] = __float2bfloat16((v1.x - mu) * rstd * g1.x + b1.x);
    o[5] = __float2bfloat16((v1.y - mu) * rstd * g1.y + b1.y);
    o[6] = __float2bfloat16((v1.z - mu) * rstd * g1.z + b1.z);
    o[7] = __float2bfloat16((v1.w - mu) * rstd * g1.w + b1.w);
}

// ---------------------------------------------------------------------------
// Weight transpose + cast: W[K,N] f32 -> Wt[N,K] bf16.  block (32,8)
// ---------------------------------------------------------------------------
__global__ void wtrans_kernel(const float* __restrict__ W, bf16* __restrict__ Wt,
                              int K, int N)
{
    __shared__ float t[32][33];
    int tx = threadIdx.x, ty = threadIdx.y;
    int n0 = blockIdx.x * 32, k0 = blockIdx.y * 32;
    for (int j = 0; j < 32; j += 8)
        t[ty + j][tx] = W[(size_t)(k0 + ty + j) * N + n0 + tx];
    __syncthreads();
    for (int j = 0; j < 32; j += 8)
        Wt[(size_t)(n0 + ty + j) * K + k0 + tx] = __float2bfloat16(t[tx][ty + j]);
}

// Batched square (512x512) weight transpose: z picks which of the 4 weights.
__global__ void wtrans4_kernel(const float* __restrict__ Wq, const float* __restrict__ Wk,
                               const float* __restrict__ Wv, const float* __restrict__ Wo,
                               bf16* __restrict__ Wqt, bf16* __restrict__ Wkt,
                               bf16* __restrict__ Wvt, bf16* __restrict__ Wot)
{
    int z = blockIdx.z;
    const float* W = z == 0 ? Wq : (z == 1 ? Wk : (z == 2 ? Wv : Wo));
    bf16* Wt       = z == 0 ? Wqt : (z == 1 ? Wkt : (z == 2 ? Wvt : Wot));
    __shared__ float t[32][33];
    int tx = threadIdx.x, ty = threadIdx.y;
    int n0 = blockIdx.x * 32, k0 = blockIdx.y * 32;
    for (int j = 0; j < 32; j += 8)
        t[ty + j][tx] = W[(size_t)(k0 + ty + j) * D_ + n0 + tx];
    __syncthreads();
    for (int j = 0; j < 32; j += 8)
        Wt[(size_t)(n0 + ty + j) * D_ + k0 + tx] = __float2bfloat16(t[tx][ty + j]);
}

// ---------------------------------------------------------------------------
// V transpose per head: v[b*M+m][h*64+d] bf16 -> vt[(b*H+h)*64 + d][m] bf16
// ---------------------------------------------------------------------------
__global__ void vtrans_kernel(const bf16* __restrict__ v, bf16* __restrict__ vt)
{
    __shared__ bf16 t[32][33];
    int tx = threadIdx.x, ty = threadIdx.y;
    int bh = blockIdx.z, b = bh >> 3, h = bh & 7;
    int m0 = blockIdx.x * 32, d0 = blockIdx.y * 32;
    for (int j = 0; j < 32; j += 8)
        t[ty + j][tx] = v[(size_t)(b * M_ + m0 + ty + j) * D_ + h * DH_ + d0 + tx];
    __syncthreads();
    for (int j = 0; j < 32; j += 8)
        vt[((size_t)bh * DH_ + d0 + ty + j) * M_ + m0 + tx] = t[tx][ty + j];
}

// ---------------------------------------------------------------------------
// Generic GEMM: C[M,N] = epilogue(A[M,K] @ Bt[N,K]^T + bias)
// 128x128 tile, 4 waves (2x2), BK=32.
// ---------------------------------------------------------------------------
#define BM 128
#define BN 128
#define BK 32
#define LDK 40            // padded LDS row length in bf16 elems (80 B)

#define GEMM_BODY(Aptr, Btptr, KK, EPILOGUE)                                         \
    __shared__ bf16 As[BM * LDK];                                                    \
    __shared__ bf16 Bs[BN * LDK];                                                    \
    int t = threadIdx.x;                                                             \
    int lane = t & 63, wave = t >> 6;                                                \
    int wm = wave >> 1, wn = wave & 1;                                               \
    int r16 = lane & 15, g = lane >> 4;                                              \
    int m0 = blockIdx.x * BM, n0 = blockIdx.y * BN;                                  \
    f32x4 acc[4][4] = {};                                                            \
    for (int k0 = 0; k0 < (KK); k0 += BK) {                                          \
        __syncthreads();                                                             \
        for (int it = 0; it < 2; ++it) {                                             \
            int c = it * 256 + t;                                                    \
            int row = c >> 2, ko = (c & 3) * 8;                                      \
            uint4 dA = *(const uint4*)((Aptr)  + (size_t)(m0 + row) * (KK) + k0 + ko); \
            *(uint4*)((char*)As + row * (LDK * 2) + ko * 2) = dA;                    \
            uint4 dB = *(const uint4*)((Btptr) + (size_t)(n0 + row) * (KK) + k0 + ko); \
            *(uint4*)((char*)Bs + row * (LDK * 2) + ko * 2) = dB;                    \
        }                                                                            \
        __syncthreads();                                                             \
        bf16x8 af[4], bfr[4];                                                        \
        for (int i = 0; i < 4; ++i)                                                  \
            af[i]  = *(const bf16x8*)((char*)As + (wm * 64 + i * 16 + r16) * (LDK * 2) + g * 16); \
        for (int i = 0; i < 4; ++i)                                                  \
            bfr[i] = *(const bf16x8*)((char*)Bs + (wn * 64 + i * 16 + r16) * (LDK * 2) + g * 16); \
        for (int i = 0; i < 4; ++i)                                                  \
            for (int j = 0; j < 4; ++j)                                              \
                acc[i][j] = __builtin_amdgcn_mfma_f32_16x16x32_bf16(af[i], bfr[j], acc[i][j], 0, 0, 0); \
    }                                                                                \
    for (int i = 0; i < 4; ++i) {                                                    \
        int rb = m0 + wm * 64 + i * 16 + g * 4;                                      \
        for (int j = 0; j < 4; ++j) {                                                \
            int cb = n0 + wn * 64 + j * 16 + r16;                                    \
            float bia = bias[cb];                                                    \
            for (int e = 0; e < 4; ++e) {                                            \
                int rr = rb + e;                                                     \
                float val = acc[i][j][e] + bia;                                      \
                EPILOGUE                                                             \
            }                                                                        \
        }                                                                            \
    }

template<bool GELU, bool RESID, bool ROWMASK, bool OUTBF>
__global__ __launch_bounds__(256) void gemm_bt(
    const bf16* __restrict__ A, const bf16* __restrict__ Bt,
    const float* __restrict__ bias, const float* __restrict__ resid,
    const float* __restrict__ rowmask,
    bf16* __restrict__ outb, float* __restrict__ outf,
    int Mr, int Nn, int K)
{
    GEMM_BODY(A, Bt, K,
        if (GELU)    val = 0.5f * val * (1.f + erff(val * 0.70710678118654752f));
        if (RESID)   val += resid[(size_t)rr * Nn + cb];
        if (ROWMASK) val *= rowmask[rr];
        if (OUTBF)   outb[(size_t)rr * Nn + cb] = __float2bfloat16(val);
        else         outf[(size_t)rr * Nn + cb] = val;
    )
}

// Batched Q/K/V projection: blockIdx.z selects Q, K, or V. One launch.
__global__ __launch_bounds__(256) void gemm_qkv(
    const bf16* __restrict__ xn, const bf16* __restrict__ yn,
    const bf16* __restrict__ Wqt, const bf16* __restrict__ Wkt, const bf16* __restrict__ Wvt,
    const float* __restrict__ bq, const float* __restrict__ bk, const float* __restrict__ bv,
    const float* __restrict__ mask_x, const float* __restrict__ mask_y,
    bf16* __restrict__ qb, bf16* __restrict__ kb, bf16* __restrict__ vb)
{
    int z = blockIdx.z;
    const bf16* A        = z == 0 ? xn : yn;
    const bf16* Bt       = z == 0 ? Wqt : (z == 1 ? Wkt : Wvt);
    const float* bias    = z == 0 ? bq  : (z == 1 ? bk  : bv);
    const float* rowmask = z == 0 ? mask_x : mask_y;
    bf16* outb           = z == 0 ? qb  : (z == 1 ? kb  : vb);
    GEMM_BODY(A, Bt, D_,
        val *= rowmask[rr];
        outb[(size_t)rr * D_ + cb] = __float2bfloat16(val);
    )
}

// ---------------------------------------------------------------------------
// Flash attention, swapped orientation (S^T = K·Q): softmax is in-register.
// grid (N/64, B*H, SPLIT), block 256 = 4 waves, 16 q-rows per wave.
// Lane layout: ql = lane&15 (q-row), gg = lane>>4 (k-group).
// sacc[nf][e] = S^T[key = nf*16+4*gg+e][q = ql] -> per-lane row softmax:
// 15 in-lane max + 2 shfl (xor16, xor32); m,l are per-lane scalars.
// P stored to LDS as [q][key] via packed ds_write_b64; PV uses V^T as A,
// P as B -> cacc[df][e] = ctx^T[d = df*16+4gg+e][q = ql] (float4 stores).
// ---------------------------------------------------------------------------
__global__ __launch_bounds__(256) void attn_kernel(
    const bf16* __restrict__ q, const bf16* __restrict__ kk,
    const bf16* __restrict__ vt, float* __restrict__ num,
    float* __restrict__ ml)
{
    int bh = blockIdx.y, b = bh >> 3, h = bh & 7;
    int n0 = blockIdx.x * 64;
    int sp = blockIdx.z;
    int t = threadIdx.x, lane = t & 63, wave = t >> 6;
    int ql = lane & 15, gg = lane >> 4;

    __shared__ __align__(16) bf16 plds[4][16][72];   // per-wave P tile [q][key]

    // Q fragment (B-operand), pre-scaled by 1/sqrt(dh) = 0.125 (exact in bf16)
    int qrow = b * N_ + n0 + wave * 16 + ql;
    bf16x8 qf[2];
    for (int ks = 0; ks < 2; ++ks) {
        bf16x8 qv = *(const bf16x8*)(q + (size_t)qrow * D_ + h * DH_ + ks * 32 + gg * 8);
        for (int j = 0; j < 8; ++j) qv[j] = (__bf16)((float)qv[j] * 0.125f);
        qf[ks] = qv;
    }

    f32x4 cacc[4] = {};
    float mrow = -1e30f, lrow = 0.f;

    const bf16* kbase = kk + (size_t)(b * M_ + sp * KV_PER) * D_ + h * DH_;
    const bf16* vtb   = vt + (size_t)bh * DH_ * M_ + sp * KV_PER;

    for (int tt = 0; tt < NT; ++tt) {
        // ---- loads for this tile (issued up front, overlap with MFMA) ----
        const bf16* kt = kbase + (size_t)(tt * 64) * D_;
        bf16x8 kf[8], vf[8];
#pragma unroll
        for (int nf = 0; nf < 4; ++nf)
#pragma unroll
            for (int ks = 0; ks < 2; ++ks)
                kf[nf * 2 + ks] = *(const bf16x8*)(kt + (size_t)(nf * 16 + ql) * D_ + ks * 32 + gg * 8);
#pragma unroll
        for (int df = 0; df < 4; ++df)
#pragma unroll
            for (int ks = 0; ks < 2; ++ks)
                vf[df * 2 + ks] = *(const bf16x8*)(vtb + (size_t)(df * 16 + ql) * M_ + tt * 64 + ks * 32 + gg * 8);

        // ---- QK^T (swapped: K is A, Q is B) ----
        f32x4 sacc[4] = {};
        __builtin_amdgcn_s_setprio(1);
#pragma unroll
        for (int nf = 0; nf < 4; ++nf) {
            sacc[nf] = __builtin_amdgcn_mfma_f32_16x16x32_bf16(kf[nf * 2 + 0], qf[0], sacc[nf], 0, 0, 0);
            sacc[nf] = __builtin_amdgcn_mfma_f32_16x16x32_bf16(kf[nf * 2 + 1], qf[1], sacc[nf], 0, 0, 0);
        }
        __builtin_amdgcn_s_setprio(0);

        // ---- online softmax, per-lane (q = ql fixed) ----
        float m01 = fmaxf(fmaxf(fmaxf(sacc[0][0], sacc[0][1]), fmaxf(sacc[0][2], sacc[0][3])),
                          fmaxf(fmaxf(sacc[1][0], sacc[1][1]), fmaxf(sacc[1][2], sacc[1][3])));
        float m23 = fmaxf(fmaxf(fmaxf(sacc[2][0], sacc[2][1]), fmaxf(sacc[2][2], sacc[2][3])),
                          fmaxf(fmaxf(sacc[3][0], sacc[3][1]), fmaxf(sacc[3][2], sacc[3][3])));
        float tmax = fmaxf(m01, m23);
        tmax = fmaxf(tmax, __shfl_xor(tmax, 16, 64));
        tmax = fmaxf(tmax, __shfl_xor(tmax, 32, 64));
        float mnew = fmaxf(mrow, tmax);
        float scl  = __expf(mrow - mnew);
        mrow = mnew;

        float p[4][4];
        float ps = 0.f;
#pragma unroll
        for (int nf = 0; nf < 4; ++nf)
#pragma unroll
            for (int e = 0; e < 4; ++e) {
                p[nf][e] = __expf(sacc[nf][e] - mnew);
                ps += p[nf][e];
            }
        ps += __shfl_xor(ps, 16, 64);
        ps += __shfl_xor(ps, 32, 64);
        lrow = lrow * scl + ps;
#pragma unroll
        for (int df = 0; df < 4; ++df)
#pragma unroll
            for (int e = 0; e < 4; ++e) cacc[df][e] *= scl;

        // ---- pack P to bf16 and store [q][key] (4 x ds_write_b64) ----
#pragma unroll
        for (int nf = 0; nf < 4; ++nf) {
            bf16x4v w;
            w[0] = (__bf16)p[nf][0]; w[1] = (__bf16)p[nf][1];
            w[2] = (__bf16)p[nf][2]; w[3] = (__bf16)p[nf][3];
            *(bf16x4v*)(&plds[wave][ql][nf * 16 + 4 * gg]) = w;
        }

        // ---- PV: V^T is A, P is B ----
        __builtin_amdgcn_s_setprio(1);
#pragma unroll
        for (int ks = 0; ks < 2; ++ks) {
            bf16x8 pf = *(const bf16x8*)((const char*)&plds[wave][0][0] + ql * 144 + ks * 64 + gg * 16);
#pragma unroll
            for (int df = 0; df < 4; ++df)
                cacc[df] = __builtin_amdgcn_mfma_f32_16x16x32_bf16(vf[df * 2 + ks], pf, cacc[df], 0, 0, 0);
        }
        __builtin_amdgcn_s_setprio(0);
    }

    // ---- unnormalized numerator (f32, float4 stores) + per-row (m, l) ----
    float* nb = num + (size_t)sp * ROWS * D_ + (size_t)qrow * D_ + h * DH_;
#pragma unroll
    for (int df = 0; df < 4; ++df)
        *(f32x4*)(nb + df * 16 + 4 * gg) = cacc[df];
    if (lane < 16) {
        size_t off = ((size_t)(sp * (B_ * H_) + bh) * N_ + (n0 + wave * 16 + ql)) * 2;
        ml[off] = mrow; ml[off + 1] = lrow;
    }
}

// Combine the SPLIT partials -> bf16 ctx
__global__ __launch_bounds__(256) void attn_combine(
    const float* __restrict__ num, const float* __restrict__ ml,
    bf16* __restrict__ ctx)
{
    int idx = blockIdx.x * 256 + threadIdx.x;
    int row = idx >> 7;              // 128 four-col chunks per row
    int c4  = (idx & 127) << 2;
    int b = row >> 11, n = row & (N_ - 1);
    int h = c4 >> 6;
    int bh = (b << 3) + h;
    const float* ml0 = ml + ((size_t)bh * N_ + n) * 2;
    const float* ml1 = ml + ((size_t)(B_ * H_ + bh) * N_ + n) * 2;
    float m0 = ml0[0], l0 = ml0[1];
    float m1 = ml1[0], l1 = ml1[1];
    float mx = fmaxf(m0, m1);
    float w0 = __expf(m0 - mx), w1 = __expf(m1 - mx);
    float inv = 1.f / (w0 * l0 + w1 * l1);
    float4 a  = *(const float4*)(num + (size_t)row * D_ + c4);
    float4 bb = *(const float4*)(num + (size_t)ROWS * D_ + (size_t)row * D_ + c4);
    bf16* o = ctx + (size_t)row * D_ + c4;
    o[0] = __float2bfloat16((w0 * a.x + w1 * bb.x) * inv);
    o[1] = __float2bfloat16((w0 * a.y + w1 * bb.y) * inv);
    o[2] = __float2bfloat16((w0 * a.z + w1 * bb.z) * inv);
    o[3] = __float2bfloat16((w0 * a.w + w1 * bb.w) * inv);
}

// ---------------------------------------------------------------------------
extern "C" void kernel_launch(void* const* d_in, const int* in_sizes, int n_in,
                              void* d_out, int out_size, void* d_ws, size_t ws_size,
                              hipStream_t stream)
{
    const float* x      = (const float*)d_in[0];
    const float* y      = (const float*)d_in[1];
    const float* mask_x = (const float*)d_in[2];
    const float* mask_y = (const float*)d_in[3];
    const float* Wq = (const float*)d_in[4];  const float* bq = (const float*)d_in[5];
    const float* Wk = (const float*)d_in[6];  const float* bk = (const float*)d_in[7];
    const float* Wv = (const float*)d_in[8];  const float* bv = (const float*)d_in[9];
    const float* Wo = (const float*)d_in[10]; const float* bo = (const float*)d_in[11];
    const float* W1 = (const float*)d_in[12]; const float* b1 = (const float*)d_in[13];
    const float* W2 = (const float*)d_in[14]; const float* b2 = (const float*)d_in[15];
    const float* ln1g = (const float*)d_in[16]; const float* ln1b = (const float*)d_in[17];
    const float* ln2g = (const float*)d_in[18]; const float* ln2b = (const float*)d_in[19];

    char* ws = (char*)d_ws;
    const size_t SZA = (size_t)ROWS * D_ * 2;     // 4 MiB bf16 activation
    bf16* xn   = (bf16*)ws;            ws += SZA;
    bf16* yn   = (bf16*)ws;            ws += SZA;
    bf16* qb   = (bf16*)ws;            ws += SZA;
    bf16* kb   = (bf16*)ws;            ws += SZA;
    bf16* vb   = (bf16*)ws;            ws += SZA;
    bf16* vtb  = (bf16*)ws;            ws += SZA;
    bf16* ctxb = (bf16*)ws;            ws += SZA;
    bf16* xn2  = (bf16*)ws;            ws += SZA;
    bf16* hff  = (bf16*)ws;            ws += (size_t)ROWS * F_ * 2;
    float* x1  = (float*)ws;           ws += (size_t)ROWS * D_ * 4;
    bf16* Wqt = (bf16*)ws;             ws += (size_t)D_ * D_ * 2;
    bf16* Wkt = (bf16*)ws;             ws += (size_t)D_ * D_ * 2;
    bf16* Wvt = (bf16*)ws;             ws += (size_t)D_ * D_ * 2;
    bf16* Wot = (bf16*)ws;             ws += (size_t)D_ * D_ * 2;
    bf16* W1t = (bf16*)ws;             ws += (size_t)D_ * F_ * 2;
    bf16* W2t = (bf16*)ws;             ws += (size_t)F_ * D_ * 2;
    float* num = (float*)ws;           ws += (size_t)SPLIT * ROWS * D_ * 4;
    float* mlb = (float*)ws;           ws += (size_t)SPLIT * B_ * H_ * N_ * 2 * 4;

    dim3 tb(32, 8);
    wtrans4_kernel<<<dim3(D_ / 32, D_ / 32, 4), tb, 0, stream>>>(
        Wq, Wk, Wv, Wo, Wqt, Wkt, Wvt, Wot);
    wtrans_kernel<<<dim3(F_ / 32, D_ / 32), tb, 0, stream>>>(W1, W1t, D_, F_);
    wtrans_kernel<<<dim3(D_ / 32, F_ / 32), tb, 0, stream>>>(W2, W2t, F_, D_);

    ln_kernel<<<ROWS / 4, 256, 0, stream>>>(x, ln1g, ln1b, xn);
    ln_kernel<<<ROWS / 4, 256, 0, stream>>>(y, ln1g, ln1b, yn);

    // Q/K/V projections, one batched launch (z = 0,1,2)
    gemm_qkv<<<dim3(ROWS / BM, D_ / BN, 3), 256, 0, stream>>>(
        xn, yn, Wqt, Wkt, Wvt, bq, bk, bv, mask_x, mask_y, qb, kb, vb);

    vtrans_kernel<<<dim3(M_ / 32, DH_ / 32, B_ * H_), tb, 0, stream>>>(vb, vtb);

    attn_kernel<<<dim3(N_ / 64, B_ * H_, SPLIT), 256, 0, stream>>>(qb, kb, vtb, num, mlb);
    attn_combine<<<(ROWS * D_ / 4) / 256, 256, 0, stream>>>(num, mlb, ctxb);

    // out-proj + residual(x) -> x1 (f32)
    gemm_bt<false, true, false, false><<<dim3(ROWS / BM, D_ / BN), 256, 0, stream>>>(
        ctxb, Wot, bo, x, nullptr, nullptr, x1, ROWS, D_, D_);

    ln_kernel<<<ROWS / 4, 256, 0, stream>>>(x1, ln2g, ln2b, xn2);

    // MLP1 + GELU -> hff (bf16)
    gemm_bt<true, false, false, true><<<dim3(ROWS / BM, F_ / BN), 256, 0, stream>>>(
        xn2, W1t, b1, nullptr, nullptr, hff, nullptr, ROWS, F_, D_);

    // MLP2 + residual(x1) -> d_out (f32)
    gemm_bt<false, true, false, false><<<dim3(ROWS / BM, D_ / BN), 256, 0, stream>>>(
        hff, W2t, b2, x1, nullptr, nullptr, (float*)d_out, ROWS, D_, F_);
}

// Round 6
// 176.988 us; speedup vs baseline: 1.5926x; 1.4047x over previous
//
#include <hip/hip_runtime.h>
#include <hip/hip_bf16.h>

// Problem constants
#define B_  2
#define N_  2048
#define M_  2048
#define D_  512
#define H_  8
#define F_  2048
#define DH_ 64
#define ROWS 4096   // B_*N_ == B_*M_

#define SPLIT 4
#define KV_PER (M_ / SPLIT)   // 512
#define NT (KV_PER / 64)      // 8 tiles of 64 keys

typedef __bf16 bf16x8 __attribute__((ext_vector_type(8)));
typedef __bf16 bf16x4v __attribute__((ext_vector_type(4)));
typedef float  f32x4  __attribute__((ext_vector_type(4)));
using bf16 = __hip_bfloat16;

// ---------------------------------------------------------------------------
// LayerNorm: one wave per row of 512 f32, output bf16.
// ---------------------------------------------------------------------------
__global__ __launch_bounds__(256) void ln_kernel(
    const float* __restrict__ in, const float* __restrict__ gam,
    const float* __restrict__ bet, bf16* __restrict__ out)
{
    int wave = threadIdx.x >> 6, lane = threadIdx.x & 63;
    int row  = blockIdx.x * 4 + wave;
    const float* p = in + (size_t)row * D_ + lane * 8;
    float4 v0 = *(const float4*)p;
    float4 v1 = *(const float4*)(p + 4);
    float s  = v0.x + v0.y + v0.z + v0.w + v1.x + v1.y + v1.z + v1.w;
    float ss = v0.x*v0.x + v0.y*v0.y + v0.z*v0.z + v0.w*v0.w
             + v1.x*v1.x + v1.y*v1.y + v1.z*v1.z + v1.w*v1.w;
    for (int m = 1; m < 64; m <<= 1) {
        s  += __shfl_xor(s,  m, 64);
        ss += __shfl_xor(ss, m, 64);
    }
    float mu   = s * (1.f / D_);
    float var  = ss * (1.f / D_) - mu * mu;
    float rstd = rsqrtf(var + 1e-6f);
    int c = lane * 8;
    float4 g0 = *(const float4*)(gam + c), g1 = *(const float4*)(gam + c + 4);
    float4 b0 = *(const float4*)(bet + c), b1 = *(const float4*)(bet + c + 4);
    bf16* o = out + (size_t)row * D_ + c;
    o[0] = __float2bfloat16((v0.x - mu) * rstd * g0.x + b0.x);
    o[1] = __float2bfloat16((v0.y - mu) * rstd * g0.y + b0.y);
    o[2] = __float2bfloat16((v0.z - mu) * rstd * g0.z + b0.z);
    o[3] = __float2bfloat16((v0.w - mu) * rstd * g0.w + b0.w);
    o[4] = __float2bfloat16((v1.x - mu) * rstd * g1.x + b1.x);
    o[5] = __float2bfloat16((v1.y - mu) * rstd * g1.y + b1.y);
    o[6] = __float2bfloat16((v1.z - mu) * rstd * g1.z + b1.z);
    o[7] = __float2bfloat16((v1.w - mu) * rstd * g1.w + b1.w);
}

// ---------------------------------------------------------------------------
// Weight transpose + cast: W[K,N] f32 -> Wt[N,K] bf16.  block (32,8)
// ---------------------------------------------------------------------------
__global__ void wtrans_kernel(const float* __restrict__ W, bf16* __restrict__ Wt,
                              int K, int N)
{
    __shared__ float t[32][33];
    int tx = threadIdx.x, ty = threadIdx.y;
    int n0 = blockIdx.x * 32, k0 = blockIdx.y * 32;
    for (int j = 0; j < 32; j += 8)
        t[ty + j][tx] = W[(size_t)(k0 + ty + j) * N + n0 + tx];
    __syncthreads();
    for (int j = 0; j < 32; j += 8)
        Wt[(size_t)(n0 + ty + j) * K + k0 + tx] = __float2bfloat16(t[tx][ty + j]);
}

// Batched square (512x512) weight transpose: z picks which of the 4 weights.
__global__ void wtrans4_kernel(const float* __restrict__ Wq, const float* __restrict__ Wk,
                               const float* __restrict__ Wv, const float* __restrict__ Wo,
                               bf16* __restrict__ Wqt, bf16* __restrict__ Wkt,
                               bf16* __restrict__ Wvt, bf16* __restrict__ Wot)
{
    int z = blockIdx.z;
    const float* W = z == 0 ? Wq : (z == 1 ? Wk : (z == 2 ? Wv : Wo));
    bf16* Wt       = z == 0 ? Wqt : (z == 1 ? Wkt : (z == 2 ? Wvt : Wot));
    __shared__ float t[32][33];
    int tx = threadIdx.x, ty = threadIdx.y;
    int n0 = blockIdx.x * 32, k0 = blockIdx.y * 32;
    for (int j = 0; j < 32; j += 8)
        t[ty + j][tx] = W[(size_t)(k0 + ty + j) * D_ + n0 + tx];
    __syncthreads();
    for (int j = 0; j < 32; j += 8)
        Wt[(size_t)(n0 + ty + j) * D_ + k0 + tx] = __float2bfloat16(t[tx][ty + j]);
}

// ---------------------------------------------------------------------------
// V transpose per head: v[b*M+m][h*64+d] bf16 -> vt[(b*H+h)*64 + d][m] bf16
// ---------------------------------------------------------------------------
__global__ void vtrans_kernel(const bf16* __restrict__ v, bf16* __restrict__ vt)
{
    __shared__ bf16 t[32][33];
    int tx = threadIdx.x, ty = threadIdx.y;
    int bh = blockIdx.z, b = bh >> 3, h = bh & 7;
    int m0 = blockIdx.x * 32, d0 = blockIdx.y * 32;
    for (int j = 0; j < 32; j += 8)
        t[ty + j][tx] = v[(size_t)(b * M_ + m0 + ty + j) * D_ + h * DH_ + d0 + tx];
    __syncthreads();
    for (int j = 0; j < 32; j += 8)
        vt[((size_t)bh * DH_ + d0 + ty + j) * M_ + m0 + tx] = t[tx][ty + j];
}

// ---------------------------------------------------------------------------
// Generic GEMM: C[M,N] = epilogue(A[M,K] @ Bt[N,K]^T + bias)
// 128x128 tile, 4 waves (2x2), BK=32.
// ---------------------------------------------------------------------------
#define BM 128
#define BN 128
#define BK 32
#define LDK 40            // padded LDS row length in bf16 elems (80 B)

#define GEMM_BODY(Aptr, Btptr, KK, EPILOGUE)                                         \
    __shared__ bf16 As[BM * LDK];                                                    \
    __shared__ bf16 Bs[BN * LDK];                                                    \
    int t = threadIdx.x;                                                             \
    int lane = t & 63, wave = t >> 6;                                                \
    int wm = wave >> 1, wn = wave & 1;                                               \
    int r16 = lane & 15, g = lane >> 4;                                              \
    int m0 = blockIdx.x * BM, n0 = blockIdx.y * BN;                                  \
    f32x4 acc[4][4] = {};                                                            \
    for (int k0 = 0; k0 < (KK); k0 += BK) {                                          \
        __syncthreads();                                                             \
        for (int it = 0; it < 2; ++it) {                                             \
            int c = it * 256 + t;                                                    \
            int row = c >> 2, ko = (c & 3) * 8;                                      \
            uint4 dA = *(const uint4*)((Aptr)  + (size_t)(m0 + row) * (KK) + k0 + ko); \
            *(uint4*)((char*)As + row * (LDK * 2) + ko * 2) = dA;                    \
            uint4 dB = *(const uint4*)((Btptr) + (size_t)(n0 + row) * (KK) + k0 + ko); \
            *(uint4*)((char*)Bs + row * (LDK * 2) + ko * 2) = dB;                    \
        }                                                                            \
        __syncthreads();                                                             \
        bf16x8 af[4], bfr[4];                                                        \
        for (int i = 0; i < 4; ++i)                                                  \
            af[i]  = *(const bf16x8*)((char*)As + (wm * 64 + i * 16 + r16) * (LDK * 2) + g * 16); \
        for (int i = 0; i < 4; ++i)                                                  \
            bfr[i] = *(const bf16x8*)((char*)Bs + (wn * 64 + i * 16 + r16) * (LDK * 2) + g * 16); \
        for (int i = 0; i < 4; ++i)                                                  \
            for (int j = 0; j < 4; ++j)                                              \
                acc[i][j] = __builtin_amdgcn_mfma_f32_16x16x32_bf16(af[i], bfr[j], acc[i][j], 0, 0, 0); \
    }                                                                                \
    for (int i = 0; i < 4; ++i) {                                                    \
        int rb = m0 + wm * 64 + i * 16 + g * 4;                                      \
        for (int j = 0; j < 4; ++j) {                                                \
            int cb = n0 + wn * 64 + j * 16 + r16;                                    \
            float bia = bias[cb];                                                    \
            for (int e = 0; e < 4; ++e) {                                            \
                int rr = rb + e;                                                     \
                float val = acc[i][j][e] + bia;                                      \
                EPILOGUE                                                             \
            }                                                                        \
        }                                                                            \
    }

template<bool GELU, bool RESID, bool ROWMASK, bool OUTBF>
__global__ __launch_bounds__(256) void gemm_bt(
    const bf16* __restrict__ A, const bf16* __restrict__ Bt,
    const float* __restrict__ bias, const float* __restrict__ resid,
    const float* __restrict__ rowmask,
    bf16* __restrict__ outb, float* __restrict__ outf,
    int Mr, int Nn, int K)
{
    GEMM_BODY(A, Bt, K,
        if (GELU)    val = 0.5f * val * (1.f + erff(val * 0.70710678118654752f));
        if (RESID)   val += resid[(size_t)rr * Nn + cb];
        if (ROWMASK) val *= rowmask[rr];
        if (OUTBF)   outb[(size_t)rr * Nn + cb] = __float2bfloat16(val);
        else         outf[(size_t)rr * Nn + cb] = val;
    )
}

// Batched Q/K/V projection: blockIdx.z selects Q, K, or V. One launch.
__global__ __launch_bounds__(256) void gemm_qkv(
    const bf16* __restrict__ xn, const bf16* __restrict__ yn,
    const bf16* __restrict__ Wqt, const bf16* __restrict__ Wkt, const bf16* __restrict__ Wvt,
    const float* __restrict__ bq, const float* __restrict__ bk, const float* __restrict__ bv,
    const float* __restrict__ mask_x, const float* __restrict__ mask_y,
    bf16* __restrict__ qb, bf16* __restrict__ kb, bf16* __restrict__ vb)
{
    int z = blockIdx.z;
    const bf16* A        = z == 0 ? xn : yn;
    const bf16* Bt       = z == 0 ? Wqt : (z == 1 ? Wkt : Wvt);
    const float* bias    = z == 0 ? bq  : (z == 1 ? bk  : bv);
    const float* rowmask = z == 0 ? mask_x : mask_y;
    bf16* outb           = z == 0 ? qb  : (z == 1 ? kb  : vb);
    GEMM_BODY(A, Bt, D_,
        val *= rowmask[rr];
        outb[(size_t)rr * D_ + cb] = __float2bfloat16(val);
    )
}

// ---------------------------------------------------------------------------
// Flash attention (swapped S^T = K*Q), LDS-staged double-buffered K/V with
// XOR swizzle, reg-staged (T14): global loads for tile t+1 issue before the
// barrier+compute of tile t; ds_write into buf^1 after compute.
// grid (N/128, B*H, SPLIT), block 256 = 4 waves; each wave owns 32 q-rows
// (2 fragments). 64 keys per tile, KV_PER=512 keys per block.
// K LDS tile [64 key][64 d] bf16, 128B rows, byte ^= ((row&7)<<4) swizzle.
// V LDS tile [64 d][64 key] bf16, same swizzle.
// ---------------------------------------------------------------------------
__global__ __launch_bounds__(256, 3) void attn_kernel(
    const bf16* __restrict__ q, const bf16* __restrict__ kk,
    const bf16* __restrict__ vt, float* __restrict__ num,
    float* __restrict__ ml)
{
    int bh = blockIdx.y, b = bh >> 3, h = bh & 7;
    int n0 = blockIdx.x * 128;
    int sp = blockIdx.z;
    int t = threadIdx.x, lane = t & 63, wave = t >> 6;
    int ql = lane & 15, gg = lane >> 4;

    __shared__ __align__(16) char KsB[2][64 * 128];   // [key][d] swizzled
    __shared__ __align__(16) char VsB[2][64 * 128];   // [d][key] swizzled
    __shared__ __align__(16) bf16 plds[4][16][72];    // per-wave P tile [q][key]

    // Q fragments (B-operand), pre-scaled by 1/sqrt(dh) = 0.125 (exact)
    bf16x8 qf0[2], qf1[2];
    {
        int qr0 = b * N_ + n0 + wave * 32 + ql;
        for (int ks = 0; ks < 2; ++ks) {
            bf16x8 qv = *(const bf16x8*)(q + (size_t)qr0 * D_ + h * DH_ + ks * 32 + gg * 8);
            for (int j = 0; j < 8; ++j) qv[j] = (__bf16)((float)qv[j] * 0.125f);
            qf0[ks] = qv;
            bf16x8 qw = *(const bf16x8*)(q + (size_t)(qr0 + 16) * D_ + h * DH_ + ks * 32 + gg * 8);
            for (int j = 0; j < 8; ++j) qw[j] = (__bf16)((float)qw[j] * 0.125f);
            qf1[ks] = qw;
        }
    }

    f32x4 cacc0[4] = {}, cacc1[4] = {};
    float m0r = -1e30f, l0r = 0.f, m1r = -1e30f, l1r = 0.f;

    const bf16* kbase = kk + (size_t)(b * M_ + sp * KV_PER) * D_ + h * DH_;
    const bf16* vtb   = vt + (size_t)bh * DH_ * M_ + sp * KV_PER;

    // staging slot decomposition (each thread: slots t and t+256 of 512)
    const int k0r = t >> 3,          kc0 = t & 7;          // slot t
    const int k1r = (t >> 3) + 32;   // slot t+256 (same col)
    // swizzled LDS byte offsets for the two slots (row*128 + (col^(row&7))*16)
    const int wofs0 = k0r * 128 + ((kc0 ^ (k0r & 7)) << 4);
    const int wofs1 = k1r * 128 + ((kc0 ^ (k1r & 7)) << 4);
    // fragment-read swizzled column offsets: ((ks*4+gg)^(ql&7))<<4
    const int rsw0 = ((gg     ^ (ql & 7)) << 4);
    const int rsw1 = (((4 + gg) ^ (ql & 7)) << 4);

#define STAGE_LOAD(tt)                                                              \
    kw0 = *(const uint4*)(kbase + (size_t)((tt) * 64 + k0r) * D_ + kc0 * 8);        \
    kw1 = *(const uint4*)(kbase + (size_t)((tt) * 64 + k1r) * D_ + kc0 * 8);        \
    vw0 = *(const uint4*)(vtb + (size_t)k0r * M_ + (tt) * 64 + kc0 * 8);            \
    vw1 = *(const uint4*)(vtb + (size_t)k1r * M_ + (tt) * 64 + kc0 * 8);

#define STAGE_WRITE(buf)                                                            \
    *(uint4*)(KsB[buf] + wofs0) = kw0;                                              \
    *(uint4*)(KsB[buf] + wofs1) = kw1;                                              \
    *(uint4*)(VsB[buf] + wofs0) = vw0;                                              \
    *(uint4*)(VsB[buf] + wofs1) = vw1;

#define SOFTMAX_PV(S, MR, LR, CACC, QTAG)                                           \
    {                                                                               \
        float tmax = fmaxf(                                                         \
            fmaxf(fmaxf(fmaxf(S[0][0], S[0][1]), fmaxf(S[0][2], S[0][3])),          \
                  fmaxf(fmaxf(S[1][0], S[1][1]), fmaxf(S[1][2], S[1][3]))),         \
            fmaxf(fmaxf(fmaxf(S[2][0], S[2][1]), fmaxf(S[2][2], S[2][3])),          \
                  fmaxf(fmaxf(S[3][0], S[3][1]), fmaxf(S[3][2], S[3][3]))));        \
        tmax = fmaxf(tmax, __shfl_xor(tmax, 16, 64));                               \
        tmax = fmaxf(tmax, __shfl_xor(tmax, 32, 64));                               \
        float mnew = fmaxf(MR, tmax);                                               \
        float scl  = __expf(MR - mnew);                                             \
        MR = mnew;                                                                  \
        float p[4][4]; float ps = 0.f;                                              \
        for (int nf = 0; nf < 4; ++nf)                                              \
            for (int e = 0; e < 4; ++e) { p[nf][e] = __expf(S[nf][e] - mnew); ps += p[nf][e]; } \
        ps += __shfl_xor(ps, 16, 64);                                               \
        ps += __shfl_xor(ps, 32, 64);                                               \
        LR = LR * scl + ps;                                                         \
        for (int df = 0; df < 4; ++df)                                              \
            for (int e = 0; e < 4; ++e) CACC[df][e] *= scl;                         \
        for (int nf = 0; nf < 4; ++nf) {                                            \
            bf16x4v w;                                                              \
            w[0] = (__bf16)p[nf][0]; w[1] = (__bf16)p[nf][1];                       \
            w[2] = (__bf16)p[nf][2]; w[3] = (__bf16)p[nf][3];                       \
            *(bf16x4v*)(&plds[wave][ql][nf * 16 + 4 * gg]) = w;                     \
        }                                                                           \
        __builtin_amdgcn_s_setprio(1);                                              \
        for (int ks = 0; ks < 2; ++ks) {                                            \
            bf16x8 pf = *(const bf16x8*)((const char*)&plds[wave][0][0]             \
                                         + ql * 144 + ks * 64 + gg * 16);           \
            for (int df = 0; df < 4; ++df)                                          \
                CACC[df] = __builtin_amdgcn_mfma_f32_16x16x32_bf16(                 \
                    vf[df * 2 + ks], pf, CACC[df], 0, 0, 0);                        \
        }                                                                           \
        __builtin_amdgcn_s_setprio(0);                                              \
    }

    uint4 kw0, kw1, vw0, vw1;
    STAGE_LOAD(0)
    STAGE_WRITE(0)
    int cur = 0;

    for (int tt = 0; tt < NT; ++tt) {
        if (tt + 1 < NT) { STAGE_LOAD(tt + 1) }
        __syncthreads();

        const char* Kb = KsB[cur];
        const char* Vb = VsB[cur];

        bf16x8 kf[8];
#pragma unroll
        for (int nf = 0; nf < 4; ++nf) {
            kf[nf * 2 + 0] = *(const bf16x8*)(Kb + (nf * 16 + ql) * 128 + rsw0);
            kf[nf * 2 + 1] = *(const bf16x8*)(Kb + (nf * 16 + ql) * 128 + rsw1);
        }

        f32x4 s0[4] = {}, s1[4] = {};
        __builtin_amdgcn_s_setprio(1);
#pragma unroll
        for (int nf = 0; nf < 4; ++nf) {
            s0[nf] = __builtin_amdgcn_mfma_f32_16x16x32_bf16(kf[nf * 2 + 0], qf0[0], s0[nf], 0, 0, 0);
            s0[nf] = __builtin_amdgcn_mfma_f32_16x16x32_bf16(kf[nf * 2 + 1], qf0[1], s0[nf], 0, 0, 0);
            s1[nf] = __builtin_amdgcn_mfma_f32_16x16x32_bf16(kf[nf * 2 + 0], qf1[0], s1[nf], 0, 0, 0);
            s1[nf] = __builtin_amdgcn_mfma_f32_16x16x32_bf16(kf[nf * 2 + 1], qf1[1], s1[nf], 0, 0, 0);
        }
        __builtin_amdgcn_s_setprio(0);

        bf16x8 vf[8];
#pragma unroll
        for (int df = 0; df < 4; ++df) {
            vf[df * 2 + 0] = *(const bf16x8*)(Vb + (df * 16 + ql) * 128 + rsw0);
            vf[df * 2 + 1] = *(const bf16x8*)(Vb + (df * 16 + ql) * 128 + rsw1);
        }

        SOFTMAX_PV(s0, m0r, l0r, cacc0, 0)
        SOFTMAX_PV(s1, m1r, l1r, cacc1, 1)

        if (tt + 1 < NT) { STAGE_WRITE(cur ^ 1) }
        cur ^= 1;
    }

    // ---- unnormalized numerator (f32, float4 stores) + per-row (m, l) ----
    {
        int qr0 = b * N_ + n0 + wave * 32 + ql;
        float* nb0 = num + (size_t)sp * ROWS * D_ + (size_t)qr0 * D_ + h * DH_;
        float* nb1 = num + (size_t)sp * ROWS * D_ + (size_t)(qr0 + 16) * D_ + h * DH_;
#pragma unroll
        for (int df = 0; df < 4; ++df) {
            *(f32x4*)(nb0 + df * 16 + 4 * gg) = cacc0[df];
            *(f32x4*)(nb1 + df * 16 + 4 * gg) = cacc1[df];
        }
        if (lane < 16) {
            size_t base = ((size_t)(sp * (B_ * H_) + bh) * N_ + (n0 + wave * 32 + ql)) * 2;
            ml[base] = m0r; ml[base + 1] = l0r;
            size_t base1 = ((size_t)(sp * (B_ * H_) + bh) * N_ + (n0 + wave * 32 + 16 + ql)) * 2;
            ml[base1] = m1r; ml[base1 + 1] = l1r;
        }
    }
#undef STAGE_LOAD
#undef STAGE_WRITE
#undef SOFTMAX_PV
}

// Combine the SPLIT partials -> bf16 ctx
__global__ __launch_bounds__(256) void attn_combine(
    const float* __restrict__ num, const float* __restrict__ ml,
    bf16* __restrict__ ctx)
{
    int idx = blockIdx.x * 256 + threadIdx.x;
    int row = idx >> 7;              // 128 four-col chunks per row
    int c4  = (idx & 127) << 2;
    int b = row >> 11, n = row & (N_ - 1);
    int h = c4 >> 6;
    int bh = (b << 3) + h;
    float mv[SPLIT], lv[SPLIT];
#pragma unroll
    for (int sp = 0; sp < SPLIT; ++sp) {
        const float* mp = ml + ((size_t)(sp * (B_ * H_) + bh) * N_ + n) * 2;
        mv[sp] = mp[0]; lv[sp] = mp[1];
    }
    float mx = mv[0];
#pragma unroll
    for (int sp = 1; sp < SPLIT; ++sp) mx = fmaxf(mx, mv[sp]);
    float den = 0.f;
    float wsc[SPLIT];
#pragma unroll
    for (int sp = 0; sp < SPLIT; ++sp) {
        wsc[sp] = __expf(mv[sp] - mx);
        den += wsc[sp] * lv[sp];
    }
    float inv = 1.f / den;
    float ax = 0.f, ay = 0.f, az = 0.f, aw = 0.f;
#pragma unroll
    for (int sp = 0; sp < SPLIT; ++sp) {
        float4 v = *(const float4*)(num + (size_t)sp * ROWS * D_ + (size_t)row * D_ + c4);
        ax += wsc[sp] * v.x; ay += wsc[sp] * v.y;
        az += wsc[sp] * v.z; aw += wsc[sp] * v.w;
    }
    bf16* o = ctx + (size_t)row * D_ + c4;
    o[0] = __float2bfloat16(ax * inv);
    o[1] = __float2bfloat16(ay * inv);
    o[2] = __float2bfloat16(az * inv);
    o[3] = __float2bfloat16(aw * inv);
}

// ---------------------------------------------------------------------------
extern "C" void kernel_launch(void* const* d_in, const int* in_sizes, int n_in,
                              void* d_out, int out_size, void* d_ws, size_t ws_size,
                              hipStream_t stream)
{
    const float* x      = (const float*)d_in[0];
    const float* y      = (const float*)d_in[1];
    const float* mask_x = (const float*)d_in[2];
    const float* mask_y = (const float*)d_in[3];
    const float* Wq = (const float*)d_in[4];  const float* bq = (const float*)d_in[5];
    const float* Wk = (const float*)d_in[6];  const float* bk = (const float*)d_in[7];
    const float* Wv = (const float*)d_in[8];  const float* bv = (const float*)d_in[9];
    const float* Wo = (const float*)d_in[10]; const float* bo = (const float*)d_in[11];
    const float* W1 = (const float*)d_in[12]; const float* b1 = (const float*)d_in[13];
    const float* W2 = (const float*)d_in[14]; const float* b2 = (const float*)d_in[15];
    const float* ln1g = (const float*)d_in[16]; const float* ln1b = (const float*)d_in[17];
    const float* ln2g = (const float*)d_in[18]; const float* ln2b = (const float*)d_in[19];

    char* ws = (char*)d_ws;
    const size_t SZA = (size_t)ROWS * D_ * 2;     // 4 MiB bf16 activation
    bf16* xn   = (bf16*)ws;            ws += SZA;
    bf16* yn   = (bf16*)ws;            ws += SZA;
    bf16* qb   = (bf16*)ws;            ws += SZA;
    bf16* kb   = (bf16*)ws;            ws += SZA;
    bf16* vb   = (bf16*)ws;            ws += SZA;
    bf16* vtb  = (bf16*)ws;            ws += SZA;
    bf16* ctxb = (bf16*)ws;            ws += SZA;
    bf16* xn2  = (bf16*)ws;            ws += SZA;
    bf16* hff  = (bf16*)ws;            ws += (size_t)ROWS * F_ * 2;
    float* x1  = (float*)ws;           ws += (size_t)ROWS * D_ * 4;
    bf16* Wqt = (bf16*)ws;             ws += (size_t)D_ * D_ * 2;
    bf16* Wkt = (bf16*)ws;             ws += (size_t)D_ * D_ * 2;
    bf16* Wvt = (bf16*)ws;             ws += (size_t)D_ * D_ * 2;
    bf16* Wot = (bf16*)ws;             ws += (size_t)D_ * D_ * 2;
    bf16* W1t = (bf16*)ws;             ws += (size_t)D_ * F_ * 2;
    bf16* W2t = (bf16*)ws;             ws += (size_t)F_ * D_ * 2;
    float* num = (float*)ws;           ws += (size_t)SPLIT * ROWS * D_ * 4;
    float* mlb = (float*)ws;           ws += (size_t)SPLIT * B_ * H_ * N_ * 2 * 4;

    dim3 tb(32, 8);
    wtrans4_kernel<<<dim3(D_ / 32, D_ / 32, 4), tb, 0, stream>>>(
        Wq, Wk, Wv, Wo, Wqt, Wkt, Wvt, Wot);
    wtrans_kernel<<<dim3(F_ / 32, D_ / 32), tb, 0, stream>>>(W1, W1t, D_, F_);
    wtrans_kernel<<<dim3(D_ / 32, F_ / 32), tb, 0, stream>>>(W2, W2t, F_, D_);

    ln_kernel<<<ROWS / 4, 256, 0, stream>>>(x, ln1g, ln1b, xn);
    ln_kernel<<<ROWS / 4, 256, 0, stream>>>(y, ln1g, ln1b, yn);

    // Q/K/V projections, one batched launch (z = 0,1,2)
    gemm_qkv<<<dim3(ROWS / BM, D_ / BN, 3), 256, 0, stream>>>(
        xn, yn, Wqt, Wkt, Wvt, bq, bk, bv, mask_x, mask_y, qb, kb, vb);

    vtrans_kernel<<<dim3(M_ / 32, DH_ / 32, B_ * H_), tb, 0, stream>>>(vb, vtb);

    attn_kernel<<<dim3(N_ / 128, B_ * H_, SPLIT), 256, 0, stream>>>(qb, kb, vtb, num, mlb);
    attn_combine<<<(ROWS * D_ / 4) / 256, 256, 0, stream>>>(num, mlb, ctxb);

    // out-proj + residual(x) -> x1 (f32)
    gemm_bt<false, true, false, false><<<dim3(ROWS / BM, D_ / BN), 256, 0, stream>>>(
        ctxb, Wot, bo, x, nullptr, nullptr, x1, ROWS, D_, D_);

    ln_kernel<<<ROWS / 4, 256, 0, stream>>>(x1, ln2g, ln2b, xn2);

    // MLP1 + GELU -> hff (bf16)
    gemm_bt<true, false, false, true><<<dim3(ROWS / BM, F_ / BN), 256, 0, stream>>>(
        xn2, W1t, b1, nullptr, nullptr, hff, nullptr, ROWS, F_, D_);

    // MLP2 + residual(x1) -> d_out (f32)
    gemm_bt<false, true, false, false><<<dim3(ROWS / BM, D_ / BN), 256, 0, stream>>>(
        hff, W2t, b2, x1, nullptr, nullptr, (float*)d_out, ROWS, D_, F_);
}

// Round 7
// 137.106 us; speedup vs baseline: 2.0559x; 1.2909x over previous
//
#include <hip/hip_runtime.h>
#include <hip/hip_bf16.h>

// Problem constants
#define B_  2
#define N_  2048
#define M_  2048
#define D_  512
#define H_  8
#define F_  2048
#define DH_ 64
#define ROWS 4096   // B_*N_ == B_*M_

#define SPLIT 4
#define KV_PER (M_ / SPLIT)   // 512
#define NT (KV_PER / 64)      // 8 tiles of 64 keys

typedef __bf16 bf16x8 __attribute__((ext_vector_type(8)));
typedef __bf16 bf16x4v __attribute__((ext_vector_type(4)));
typedef float  f32x4  __attribute__((ext_vector_type(4)));
using bf16 = __hip_bfloat16;

// ---------------------------------------------------------------------------
// LayerNorm: one wave per row of 512 f32, output bf16.
// ---------------------------------------------------------------------------
__global__ __launch_bounds__(256) void ln_kernel(
    const float* __restrict__ in, const float* __restrict__ gam,
    const float* __restrict__ bet, bf16* __restrict__ out)
{
    int wave = threadIdx.x >> 6, lane = threadIdx.x & 63;
    int row  = blockIdx.x * 4 + wave;
    const float* p = in + (size_t)row * D_ + lane * 8;
    float4 v0 = *(const float4*)p;
    float4 v1 = *(const float4*)(p + 4);
    float s  = v0.x + v0.y + v0.z + v0.w + v1.x + v1.y + v1.z + v1.w;
    float ss = v0.x*v0.x + v0.y*v0.y + v0.z*v0.z + v0.w*v0.w
             + v1.x*v1.x + v1.y*v1.y + v1.z*v1.z + v1.w*v1.w;
    for (int m = 1; m < 64; m <<= 1) {
        s  += __shfl_xor(s,  m, 64);
        ss += __shfl_xor(ss, m, 64);
    }
    float mu   = s * (1.f / D_);
    float var  = ss * (1.f / D_) - mu * mu;
    float rstd = rsqrtf(var + 1e-6f);
    int c = lane * 8;
    float4 g0 = *(const float4*)(gam + c), g1 = *(const float4*)(gam + c + 4);
    float4 b0 = *(const float4*)(bet + c), b1 = *(const float4*)(bet + c + 4);
    bf16* o = out + (size_t)row * D_ + c;
    o[0] = __float2bfloat16((v0.x - mu) * rstd * g0.x + b0.x);
    o[1] = __float2bfloat16((v0.y - mu) * rstd * g0.y + b0.y);
    o[2] = __float2bfloat16((v0.z - mu) * rstd * g0.z + b0.z);
    o[3] = __float2bfloat16((v0.w - mu) * rstd * g0.w + b0.w);
    o[4] = __float2bfloat16((v1.x - mu) * rstd * g1.x + b1.x);
    o[5] = __float2bfloat16((v1.y - mu) * rstd * g1.y + b1.y);
    o[6] = __float2bfloat16((v1.z - mu) * rstd * g1.z + b1.z);
    o[7] = __float2bfloat16((v1.w - mu) * rstd * g1.w + b1.w);
}

// ---------------------------------------------------------------------------
// Weight transpose + cast: W[K,N] f32 -> Wt[N,K] bf16.  block (32,8)
// ---------------------------------------------------------------------------
__global__ void wtrans_kernel(const float* __restrict__ W, bf16* __restrict__ Wt,
                              int K, int N)
{
    __shared__ float t[32][33];
    int tx = threadIdx.x, ty = threadIdx.y;
    int n0 = blockIdx.x * 32, k0 = blockIdx.y * 32;
    for (int j = 0; j < 32; j += 8)
        t[ty + j][tx] = W[(size_t)(k0 + ty + j) * N + n0 + tx];
    __syncthreads();
    for (int j = 0; j < 32; j += 8)
        Wt[(size_t)(n0 + ty + j) * K + k0 + tx] = __float2bfloat16(t[tx][ty + j]);
}

// Batched square (512x512) weight transpose: z picks which of the 4 weights.
__global__ void wtrans4_kernel(const float* __restrict__ Wq, const float* __restrict__ Wk,
                               const float* __restrict__ Wv, const float* __restrict__ Wo,
                               bf16* __restrict__ Wqt, bf16* __restrict__ Wkt,
                               bf16* __restrict__ Wvt, bf16* __restrict__ Wot)
{
    int z = blockIdx.z;
    const float* W = z == 0 ? Wq : (z == 1 ? Wk : (z == 2 ? Wv : Wo));
    bf16* Wt       = z == 0 ? Wqt : (z == 1 ? Wkt : (z == 2 ? Wvt : Wot));
    __shared__ float t[32][33];
    int tx = threadIdx.x, ty = threadIdx.y;
    int n0 = blockIdx.x * 32, k0 = blockIdx.y * 32;
    for (int j = 0; j < 32; j += 8)
        t[ty + j][tx] = W[(size_t)(k0 + ty + j) * D_ + n0 + tx];
    __syncthreads();
    for (int j = 0; j < 32; j += 8)
        Wt[(size_t)(n0 + ty + j) * D_ + k0 + tx] = __float2bfloat16(t[tx][ty + j]);
}

// ---------------------------------------------------------------------------
// V transpose per head: v[b*M+m][h*64+d] bf16 -> vt[(b*H+h)*64 + d][m] bf16
// ---------------------------------------------------------------------------
__global__ void vtrans_kernel(const bf16* __restrict__ v, bf16* __restrict__ vt)
{
    __shared__ bf16 t[32][33];
    int tx = threadIdx.x, ty = threadIdx.y;
    int bh = blockIdx.z, b = bh >> 3, h = bh & 7;
    int m0 = blockIdx.x * 32, d0 = blockIdx.y * 32;
    for (int j = 0; j < 32; j += 8)
        t[ty + j][tx] = v[(size_t)(b * M_ + m0 + ty + j) * D_ + h * DH_ + d0 + tx];
    __syncthreads();
    for (int j = 0; j < 32; j += 8)
        vt[((size_t)bh * DH_ + d0 + ty + j) * M_ + m0 + tx] = t[tx][ty + j];
}

// ---------------------------------------------------------------------------
// Generic GEMM (128x128 tile, 4 waves, BK=32) — used for MLP1 only now.
// ---------------------------------------------------------------------------
#define BM 128
#define BN 128
#define BK 32
#define LDK 40            // padded LDS row length in bf16 elems (80 B)

#define GEMM_BODY(Aptr, Btptr, KK, EPILOGUE)                                         \
    __shared__ bf16 As[BM * LDK];                                                    \
    __shared__ bf16 Bs[BN * LDK];                                                    \
    int t = threadIdx.x;                                                             \
    int lane = t & 63, wave = t >> 6;                                                \
    int wm = wave >> 1, wn = wave & 1;                                               \
    int r16 = lane & 15, g = lane >> 4;                                              \
    int m0 = blockIdx.x * BM, n0 = blockIdx.y * BN;                                  \
    f32x4 acc[4][4] = {};                                                            \
    for (int k0 = 0; k0 < (KK); k0 += BK) {                                          \
        __syncthreads();                                                             \
        for (int it = 0; it < 2; ++it) {                                             \
            int c = it * 256 + t;                                                    \
            int row = c >> 2, ko = (c & 3) * 8;                                      \
            uint4 dA = *(const uint4*)((Aptr)  + (size_t)(m0 + row) * (KK) + k0 + ko); \
            *(uint4*)((char*)As + row * (LDK * 2) + ko * 2) = dA;                    \
            uint4 dB = *(const uint4*)((Btptr) + (size_t)(n0 + row) * (KK) + k0 + ko); \
            *(uint4*)((char*)Bs + row * (LDK * 2) + ko * 2) = dB;                    \
        }                                                                            \
        __syncthreads();                                                             \
        bf16x8 af[4], bfr[4];                                                        \
        for (int i = 0; i < 4; ++i)                                                  \
            af[i]  = *(const bf16x8*)((char*)As + (wm * 64 + i * 16 + r16) * (LDK * 2) + g * 16); \
        for (int i = 0; i < 4; ++i)                                                  \
            bfr[i] = *(const bf16x8*)((char*)Bs + (wn * 64 + i * 16 + r16) * (LDK * 2) + g * 16); \
        for (int i = 0; i < 4; ++i)                                                  \
            for (int j = 0; j < 4; ++j)                                              \
                acc[i][j] = __builtin_amdgcn_mfma_f32_16x16x32_bf16(af[i], bfr[j], acc[i][j], 0, 0, 0); \
    }                                                                                \
    for (int i = 0; i < 4; ++i) {                                                    \
        int rb = m0 + wm * 64 + i * 16 + g * 4;                                      \
        for (int j = 0; j < 4; ++j) {                                                \
            int cb = n0 + wn * 64 + j * 16 + r16;                                    \
            float bia = bias[cb];                                                    \
            for (int e = 0; e < 4; ++e) {                                            \
                int rr = rb + e;                                                     \
                float val = acc[i][j][e] + bia;                                      \
                EPILOGUE                                                             \
            }                                                                        \
        }                                                                            \
    }

template<bool GELU, bool RESID, bool ROWMASK, bool OUTBF>
__global__ __launch_bounds__(256) void gemm_bt(
    const bf16* __restrict__ A, const bf16* __restrict__ Bt,
    const float* __restrict__ bias, const float* __restrict__ resid,
    const float* __restrict__ rowmask,
    bf16* __restrict__ outb, float* __restrict__ outf,
    int Mr, int Nn, int K)
{
    GEMM_BODY(A, Bt, K,
        if (GELU)    val = 0.5f * val * (1.f + erff(val * 0.70710678118654752f));
        if (RESID)   val += resid[(size_t)rr * Nn + cb];
        if (ROWMASK) val *= rowmask[rr];
        if (OUTBF)   outb[(size_t)rr * Nn + cb] = __float2bfloat16(val);
        else         outf[(size_t)rr * Nn + cb] = val;
    )
}

// ---------------------------------------------------------------------------
// 64x64-tile GEMM for N=512 outputs (occupancy fix: 512+ blocks).
// 4 waves (2x2, each 32x32), BK=64, reg-staged double-buffered LDS,
// XOR-swizzled (byte ^= ((row&7)<<4)) for conflict-free ds_read_b128.
// ---------------------------------------------------------------------------
template<bool RESID, bool ROWMASK, bool OUTBF>
__device__ __forceinline__ void gemm64_body(
    const bf16* __restrict__ A, const bf16* __restrict__ Bt,
    const float* __restrict__ bias, const float* __restrict__ resid,
    const float* __restrict__ rowmask,
    bf16* __restrict__ outb, float* __restrict__ outf,
    int Nn, int K)
{
    __shared__ __align__(16) char As[2][64 * 128];
    __shared__ __align__(16) char Bs[2][64 * 128];
    int t = threadIdx.x, lane = t & 63, wave = t >> 6;
    int wm = wave >> 1, wn = wave & 1;
    int r16 = lane & 15, g = lane >> 4;
    int m0 = blockIdx.x * 64, n0 = blockIdx.y * 64;

    const int sr0 = t >> 3, sr1 = sr0 + 32, sc = t & 7;
    const int wof0 = sr0 * 128 + ((sc ^ (sr0 & 7)) << 4);
    const int wof1 = sr1 * 128 + ((sc ^ (sr1 & 7)) << 4);
    const int rsw0 = ((g     ^ (r16 & 7)) << 4);   // ks=0 chunk
    const int rsw1 = (((4 + g) ^ (r16 & 7)) << 4); // ks=1 chunk

    uint4 a0, a1, b0, b1;
#define G64_LOAD(k0)                                                         \
    a0 = *(const uint4*)(A  + (size_t)(m0 + sr0) * K + (k0) + sc * 8);       \
    a1 = *(const uint4*)(A  + (size_t)(m0 + sr1) * K + (k0) + sc * 8);       \
    b0 = *(const uint4*)(Bt + (size_t)(n0 + sr0) * K + (k0) + sc * 8);       \
    b1 = *(const uint4*)(Bt + (size_t)(n0 + sr1) * K + (k0) + sc * 8);
#define G64_WRITE(buf)                                                       \
    *(uint4*)(As[buf] + wof0) = a0;  *(uint4*)(As[buf] + wof1) = a1;         \
    *(uint4*)(Bs[buf] + wof0) = b0;  *(uint4*)(Bs[buf] + wof1) = b1;

    f32x4 acc[2][2] = {};
    G64_LOAD(0)
    G64_WRITE(0)
    int cur = 0;
    const int nit = K >> 6;
    for (int it = 0; it < nit; ++it) {
        if (it + 1 < nit) { G64_LOAD((it + 1) << 6) }
        __syncthreads();
        bf16x8 af[2][2], bfr[2][2];
#pragma unroll
        for (int i = 0; i < 2; ++i) {
            af[i][0] = *(const bf16x8*)(As[cur] + (wm * 32 + i * 16 + r16) * 128 + rsw0);
            af[i][1] = *(const bf16x8*)(As[cur] + (wm * 32 + i * 16 + r16) * 128 + rsw1);
            bfr[i][0] = *(const bf16x8*)(Bs[cur] + (wn * 32 + i * 16 + r16) * 128 + rsw0);
            bfr[i][1] = *(const bf16x8*)(Bs[cur] + (wn * 32 + i * 16 + r16) * 128 + rsw1);
        }
        __builtin_amdgcn_s_setprio(1);
#pragma unroll
        for (int i = 0; i < 2; ++i)
#pragma unroll
            for (int j = 0; j < 2; ++j) {
                acc[i][j] = __builtin_amdgcn_mfma_f32_16x16x32_bf16(af[i][0], bfr[j][0], acc[i][j], 0, 0, 0);
                acc[i][j] = __builtin_amdgcn_mfma_f32_16x16x32_bf16(af[i][1], bfr[j][1], acc[i][j], 0, 0, 0);
            }
        __builtin_amdgcn_s_setprio(0);
        if (it + 1 < nit) { G64_WRITE(cur ^ 1) }
        cur ^= 1;
    }
#undef G64_LOAD
#undef G64_WRITE

#pragma unroll
    for (int i = 0; i < 2; ++i) {
        int rb = m0 + wm * 32 + i * 16 + g * 4;
#pragma unroll
        for (int j = 0; j < 2; ++j) {
            int cb = n0 + wn * 32 + j * 16 + r16;
            float bia = bias[cb];
#pragma unroll
            for (int e = 0; e < 4; ++e) {
                int rr = rb + e;
                float val = acc[i][j][e] + bia;
                if (RESID)   val += resid[(size_t)rr * Nn + cb];
                if (ROWMASK) val *= rowmask[rr];
                if (OUTBF)   outb[(size_t)rr * Nn + cb] = __float2bfloat16(val);
                else         outf[(size_t)rr * Nn + cb] = val;
            }
        }
    }
}

template<bool RESID, bool OUTBF>
__global__ __launch_bounds__(256) void gemm64(
    const bf16* __restrict__ A, const bf16* __restrict__ Bt,
    const float* __restrict__ bias, const float* __restrict__ resid,
    bf16* __restrict__ outb, float* __restrict__ outf, int Nn, int K)
{
    gemm64_body<RESID, false, OUTBF>(A, Bt, bias, resid, nullptr, outb, outf, Nn, K);
}

// Batched Q/K/V projection on the 64x64 tile: z selects Q, K, or V.
__global__ __launch_bounds__(256) void gemm64_qkv(
    const bf16* __restrict__ xn, const bf16* __restrict__ yn,
    const bf16* __restrict__ Wqt, const bf16* __restrict__ Wkt, const bf16* __restrict__ Wvt,
    const float* __restrict__ bq, const float* __restrict__ bk, const float* __restrict__ bv,
    const float* __restrict__ mask_x, const float* __restrict__ mask_y,
    bf16* __restrict__ qb, bf16* __restrict__ kb, bf16* __restrict__ vb)
{
    int z = blockIdx.z;
    const bf16* A        = z == 0 ? xn : yn;
    const bf16* Bt       = z == 0 ? Wqt : (z == 1 ? Wkt : Wvt);
    const float* bias    = z == 0 ? bq  : (z == 1 ? bk  : bv);
    const float* rowmask = z == 0 ? mask_x : mask_y;
    bf16* outb           = z == 0 ? qb  : (z == 1 ? kb  : vb);
    gemm64_body<false, true, true>(A, Bt, bias, nullptr, rowmask, outb, nullptr, D_, D_);
}

// ---------------------------------------------------------------------------
// Flash attention (swapped S^T = K*Q), LDS-staged double-buffered K/V with
// XOR swizzle, reg-staged. grid (N/128, B*H, SPLIT), block 256 = 4 waves;
// each wave owns 32 q-rows (2 fragments). 64 keys/tile, KV_PER per block.
// ---------------------------------------------------------------------------
__global__ __launch_bounds__(256, 3) void attn_kernel(
    const bf16* __restrict__ q, const bf16* __restrict__ kk,
    const bf16* __restrict__ vt, float* __restrict__ num,
    float* __restrict__ ml)
{
    int bh = blockIdx.y, b = bh >> 3, h = bh & 7;
    int n0 = blockIdx.x * 128;
    int sp = blockIdx.z;
    int t = threadIdx.x, lane = t & 63, wave = t >> 6;
    int ql = lane & 15, gg = lane >> 4;

    __shared__ __align__(16) char KsB[2][64 * 128];   // [key][d] swizzled
    __shared__ __align__(16) char VsB[2][64 * 128];   // [d][key] swizzled
    __shared__ __align__(16) bf16 plds[4][16][72];    // per-wave P tile [q][key]

    // Q fragments (B-operand), pre-scaled by 1/sqrt(dh) = 0.125 (exact)
    bf16x8 qf0[2], qf1[2];
    {
        int qr0 = b * N_ + n0 + wave * 32 + ql;
        for (int ks = 0; ks < 2; ++ks) {
            bf16x8 qv = *(const bf16x8*)(q + (size_t)qr0 * D_ + h * DH_ + ks * 32 + gg * 8);
            for (int j = 0; j < 8; ++j) qv[j] = (__bf16)((float)qv[j] * 0.125f);
            qf0[ks] = qv;
            bf16x8 qw = *(const bf16x8*)(q + (size_t)(qr0 + 16) * D_ + h * DH_ + ks * 32 + gg * 8);
            for (int j = 0; j < 8; ++j) qw[j] = (__bf16)((float)qw[j] * 0.125f);
            qf1[ks] = qw;
        }
    }

    f32x4 cacc0[4] = {}, cacc1[4] = {};
    float m0r = -1e30f, l0r = 0.f, m1r = -1e30f, l1r = 0.f;

    const bf16* kbase = kk + (size_t)(b * M_ + sp * KV_PER) * D_ + h * DH_;
    const bf16* vtb   = vt + (size_t)bh * DH_ * M_ + sp * KV_PER;

    const int k0r = t >> 3,          kc0 = t & 7;
    const int k1r = (t >> 3) + 32;
    const int wofs0 = k0r * 128 + ((kc0 ^ (k0r & 7)) << 4);
    const int wofs1 = k1r * 128 + ((kc0 ^ (k1r & 7)) << 4);
    const int rsw0 = ((gg     ^ (ql & 7)) << 4);
    const int rsw1 = (((4 + gg) ^ (ql & 7)) << 4);

#define STAGE_LOAD(tt)                                                              \
    kw0 = *(const uint4*)(kbase + (size_t)((tt) * 64 + k0r) * D_ + kc0 * 8);        \
    kw1 = *(const uint4*)(kbase + (size_t)((tt) * 64 + k1r) * D_ + kc0 * 8);        \
    vw0 = *(const uint4*)(vtb + (size_t)k0r * M_ + (tt) * 64 + kc0 * 8);            \
    vw1 = *(const uint4*)(vtb + (size_t)k1r * M_ + (tt) * 64 + kc0 * 8);

#define STAGE_WRITE(buf)                                                            \
    *(uint4*)(KsB[buf] + wofs0) = kw0;                                              \
    *(uint4*)(KsB[buf] + wofs1) = kw1;                                              \
    *(uint4*)(VsB[buf] + wofs0) = vw0;                                              \
    *(uint4*)(VsB[buf] + wofs1) = vw1;

#define SOFTMAX_PV(S, MR, LR, CACC)                                                 \
    {                                                                               \
        float tmax = fmaxf(                                                         \
            fmaxf(fmaxf(fmaxf(S[0][0], S[0][1]), fmaxf(S[0][2], S[0][3])),          \
                  fmaxf(fmaxf(S[1][0], S[1][1]), fmaxf(S[1][2], S[1][3]))),         \
            fmaxf(fmaxf(fmaxf(S[2][0], S[2][1]), fmaxf(S[2][2], S[2][3])),          \
                  fmaxf(fmaxf(S[3][0], S[3][1]), fmaxf(S[3][2], S[3][3]))));        \
        tmax = fmaxf(tmax, __shfl_xor(tmax, 16, 64));                               \
        tmax = fmaxf(tmax, __shfl_xor(tmax, 32, 64));                               \
        float mnew = fmaxf(MR, tmax);                                               \
        float scl  = __expf(MR - mnew);                                             \
        MR = mnew;                                                                  \
        float p[4][4]; float ps = 0.f;                                              \
        for (int nf = 0; nf < 4; ++nf)                                              \
            for (int e = 0; e < 4; ++e) { p[nf][e] = __expf(S[nf][e] - mnew); ps += p[nf][e]; } \
        ps += __shfl_xor(ps, 16, 64);                                               \
        ps += __shfl_xor(ps, 32, 64);                                               \
        LR = LR * scl + ps;                                                         \
        for (int df = 0; df < 4; ++df)                                              \
            for (int e = 0; e < 4; ++e) CACC[df][e] *= scl;                         \
        for (int nf = 0; nf < 4; ++nf) {                                            \
            bf16x4v w;                                                              \
            w[0] = (__bf16)p[nf][0]; w[1] = (__bf16)p[nf][1];                       \
            w[2] = (__bf16)p[nf][2]; w[3] = (__bf16)p[nf][3];                       \
            *(bf16x4v*)(&plds[wave][ql][nf * 16 + 4 * gg]) = w;                     \
        }                                                                           \
        __builtin_amdgcn_s_setprio(1);                                              \
        for (int ks = 0; ks < 2; ++ks) {                                            \
            bf16x8 pf = *(const bf16x8*)((const char*)&plds[wave][0][0]             \
                                         + ql * 144 + ks * 64 + gg * 16);           \
            for (int df = 0; df < 4; ++df)                                          \
                CACC[df] = __builtin_amdgcn_mfma_f32_16x16x32_bf16(                 \
                    vf[df * 2 + ks], pf, CACC[df], 0, 0, 0);                        \
        }                                                                           \
        __builtin_amdgcn_s_setprio(0);                                              \
    }

    uint4 kw0, kw1, vw0, vw1;
    STAGE_LOAD(0)
    STAGE_WRITE(0)
    int cur = 0;

    for (int tt = 0; tt < NT; ++tt) {
        if (tt + 1 < NT) { STAGE_LOAD(tt + 1) }
        __syncthreads();

        const char* Kb = KsB[cur];
        const char* Vb = VsB[cur];

        bf16x8 kf[8];
#pragma unroll
        for (int nf = 0; nf < 4; ++nf) {
            kf[nf * 2 + 0] = *(const bf16x8*)(Kb + (nf * 16 + ql) * 128 + rsw0);
            kf[nf * 2 + 1] = *(const bf16x8*)(Kb + (nf * 16 + ql) * 128 + rsw1);
        }

        f32x4 s0[4] = {}, s1[4] = {};
        __builtin_amdgcn_s_setprio(1);
#pragma unroll
        for (int nf = 0; nf < 4; ++nf) {
            s0[nf] = __builtin_amdgcn_mfma_f32_16x16x32_bf16(kf[nf * 2 + 0], qf0[0], s0[nf], 0, 0, 0);
            s0[nf] = __builtin_amdgcn_mfma_f32_16x16x32_bf16(kf[nf * 2 + 1], qf0[1], s0[nf], 0, 0, 0);
            s1[nf] = __builtin_amdgcn_mfma_f32_16x16x32_bf16(kf[nf * 2 + 0], qf1[0], s1[nf], 0, 0, 0);
            s1[nf] = __builtin_amdgcn_mfma_f32_16x16x32_bf16(kf[nf * 2 + 1], qf1[1], s1[nf], 0, 0, 0);
        }
        __builtin_amdgcn_s_setprio(0);

        bf16x8 vf[8];
#pragma unroll
        for (int df = 0; df < 4; ++df) {
            vf[df * 2 + 0] = *(const bf16x8*)(Vb + (df * 16 + ql) * 128 + rsw0);
            vf[df * 2 + 1] = *(const bf16x8*)(Vb + (df * 16 + ql) * 128 + rsw1);
        }

        SOFTMAX_PV(s0, m0r, l0r, cacc0)
        SOFTMAX_PV(s1, m1r, l1r, cacc1)

        if (tt + 1 < NT) { STAGE_WRITE(cur ^ 1) }
        cur ^= 1;
    }

    {
        int qr0 = b * N_ + n0 + wave * 32 + ql;
        float* nb0 = num + (size_t)sp * ROWS * D_ + (size_t)qr0 * D_ + h * DH_;
        float* nb1 = num + (size_t)sp * ROWS * D_ + (size_t)(qr0 + 16) * D_ + h * DH_;
#pragma unroll
        for (int df = 0; df < 4; ++df) {
            *(f32x4*)(nb0 + df * 16 + 4 * gg) = cacc0[df];
            *(f32x4*)(nb1 + df * 16 + 4 * gg) = cacc1[df];
        }
        if (lane < 16) {
            size_t base = ((size_t)(sp * (B_ * H_) + bh) * N_ + (n0 + wave * 32 + ql)) * 2;
            ml[base] = m0r; ml[base + 1] = l0r;
            size_t base1 = ((size_t)(sp * (B_ * H_) + bh) * N_ + (n0 + wave * 32 + 16 + ql)) * 2;
            ml[base1] = m1r; ml[base1 + 1] = l1r;
        }
    }
#undef STAGE_LOAD
#undef STAGE_WRITE
#undef SOFTMAX_PV
}

// Combine the SPLIT partials -> bf16 ctx
__global__ __launch_bounds__(256) void attn_combine(
    const float* __restrict__ num, const float* __restrict__ ml,
    bf16* __restrict__ ctx)
{
    int idx = blockIdx.x * 256 + threadIdx.x;
    int row = idx >> 7;              // 128 four-col chunks per row
    int c4  = (idx & 127) << 2;
    int b = row >> 11, n = row & (N_ - 1);
    int h = c4 >> 6;
    int bh = (b << 3) + h;
    float mv[SPLIT], lv[SPLIT];
#pragma unroll
    for (int sp = 0; sp < SPLIT; ++sp) {
        const float* mp = ml + ((size_t)(sp * (B_ * H_) + bh) * N_ + n) * 2;
        mv[sp] = mp[0]; lv[sp] = mp[1];
    }
    float mx = mv[0];
#pragma unroll
    for (int sp = 1; sp < SPLIT; ++sp) mx = fmaxf(mx, mv[sp]);
    float den = 0.f;
    float wsc[SPLIT];
#pragma unroll
    for (int sp = 0; sp < SPLIT; ++sp) {
        wsc[sp] = __expf(mv[sp] - mx);
        den += wsc[sp] * lv[sp];
    }
    float inv = 1.f / den;
    float ax = 0.f, ay = 0.f, az = 0.f, aw = 0.f;
#pragma unroll
    for (int sp = 0; sp < SPLIT; ++sp) {
        float4 v = *(const float4*)(num + (size_t)sp * ROWS * D_ + (size_t)row * D_ + c4);
        ax += wsc[sp] * v.x; ay += wsc[sp] * v.y;
        az += wsc[sp] * v.z; aw += wsc[sp] * v.w;
    }
    bf16* o = ctx + (size_t)row * D_ + c4;
    o[0] = __float2bfloat16(ax * inv);
    o[1] = __float2bfloat16(ay * inv);
    o[2] = __float2bfloat16(az * inv);
    o[3] = __float2bfloat16(aw * inv);
}

// ---------------------------------------------------------------------------
extern "C" void kernel_launch(void* const* d_in, const int* in_sizes, int n_in,
                              void* d_out, int out_size, void* d_ws, size_t ws_size,
                              hipStream_t stream)
{
    const float* x      = (const float*)d_in[0];
    const float* y      = (const float*)d_in[1];
    const float* mask_x = (const float*)d_in[2];
    const float* mask_y = (const float*)d_in[3];
    const float* Wq = (const float*)d_in[4];  const float* bq = (const float*)d_in[5];
    const float* Wk = (const float*)d_in[6];  const float* bk = (const float*)d_in[7];
    const float* Wv = (const float*)d_in[8];  const float* bv = (const float*)d_in[9];
    const float* Wo = (const float*)d_in[10]; const float* bo = (const float*)d_in[11];
    const float* W1 = (const float*)d_in[12]; const float* b1 = (const float*)d_in[13];
    const float* W2 = (const float*)d_in[14]; const float* b2 = (const float*)d_in[15];
    const float* ln1g = (const float*)d_in[16]; const float* ln1b = (const float*)d_in[17];
    const float* ln2g = (const float*)d_in[18]; const float* ln2b = (const float*)d_in[19];

    char* ws = (char*)d_ws;
    const size_t SZA = (size_t)ROWS * D_ * 2;     // 4 MiB bf16 activation
    bf16* xn   = (bf16*)ws;            ws += SZA;
    bf16* yn   = (bf16*)ws;            ws += SZA;
    bf16* qb   = (bf16*)ws;            ws += SZA;
    bf16* kb   = (bf16*)ws;            ws += SZA;
    bf16* vb   = (bf16*)ws;            ws += SZA;
    bf16* vtb  = (bf16*)ws;            ws += SZA;
    bf16* ctxb = (bf16*)ws;            ws += SZA;
    bf16* xn2  = (bf16*)ws;            ws += SZA;
    bf16* hff  = (bf16*)ws;            ws += (size_t)ROWS * F_ * 2;
    float* x1  = (float*)ws;           ws += (size_t)ROWS * D_ * 4;
    bf16* Wqt = (bf16*)ws;             ws += (size_t)D_ * D_ * 2;
    bf16* Wkt = (bf16*)ws;             ws += (size_t)D_ * D_ * 2;
    bf16* Wvt = (bf16*)ws;             ws += (size_t)D_ * D_ * 2;
    bf16* Wot = (bf16*)ws;             ws += (size_t)D_ * D_ * 2;
    bf16* W1t = (bf16*)ws;             ws += (size_t)D_ * F_ * 2;
    bf16* W2t = (bf16*)ws;             ws += (size_t)F_ * D_ * 2;
    float* num = (float*)ws;           ws += (size_t)SPLIT * ROWS * D_ * 4;
    float* mlb = (float*)ws;           ws += (size_t)SPLIT * B_ * H_ * N_ * 2 * 4;

    dim3 tb(32, 8);
    wtrans4_kernel<<<dim3(D_ / 32, D_ / 32, 4), tb, 0, stream>>>(
        Wq, Wk, Wv, Wo, Wqt, Wkt, Wvt, Wot);
    wtrans_kernel<<<dim3(F_ / 32, D_ / 32), tb, 0, stream>>>(W1, W1t, D_, F_);
    wtrans_kernel<<<dim3(D_ / 32, F_ / 32), tb, 0, stream>>>(W2, W2t, F_, D_);

    ln_kernel<<<ROWS / 4, 256, 0, stream>>>(x, ln1g, ln1b, xn);
    ln_kernel<<<ROWS / 4, 256, 0, stream>>>(y, ln1g, ln1b, yn);

    // Q/K/V projections, one batched launch (z = 0,1,2), 64x64 tiles
    gemm64_qkv<<<dim3(ROWS / 64, D_ / 64, 3), 256, 0, stream>>>(
        xn, yn, Wqt, Wkt, Wvt, bq, bk, bv, mask_x, mask_y, qb, kb, vb);

    vtrans_kernel<<<dim3(M_ / 32, DH_ / 32, B_ * H_), tb, 0, stream>>>(vb, vtb);

    attn_kernel<<<dim3(N_ / 128, B_ * H_, SPLIT), 256, 0, stream>>>(qb, kb, vtb, num, mlb);
    attn_combine<<<(ROWS * D_ / 4) / 256, 256, 0, stream>>>(num, mlb, ctxb);

    // out-proj + residual(x) -> x1 (f32), 64x64 tiles
    gemm64<true, false><<<dim3(ROWS / 64, D_ / 64), 256, 0, stream>>>(
        ctxb, Wot, bo, x, nullptr, x1, D_, D_);

    ln_kernel<<<ROWS / 4, 256, 0, stream>>>(x1, ln2g, ln2b, xn2);

    // MLP1 + GELU -> hff (bf16), 128x128 tiles (512 blocks)
    gemm_bt<true, false, false, true><<<dim3(ROWS / BM, F_ / BN), 256, 0, stream>>>(
        xn2, W1t, b1, nullptr, nullptr, hff, nullptr, ROWS, F_, D_);

    // MLP2 + residual(x1) -> d_out (f32), 64x64 tiles
    gemm64<true, false><<<dim3(ROWS / 64, D_ / 64), 256, 0, stream>>>(
        hff, W2t, b2, x1, nullptr, (float*)d_out, D_, F_);
}

// Round 8
// 126.121 us; speedup vs baseline: 2.2349x; 1.0871x over previous
//
#include <hip/hip_runtime.h>
#include <hip/hip_bf16.h>

// Problem constants
#define B_  2
#define N_  2048
#define M_  2048
#define D_  512
#define H_  8
#define F_  2048
#define DH_ 64
#define ROWS 4096   // B_*N_ == B_*M_

#define SPLIT 2
#define KV_PER (M_ / SPLIT)   // 1024
#define NT (KV_PER / 64)      // 16 tiles of 64 keys
#define ATT_GRID (16 * 16 * SPLIT)   // n0(16) x bh(16) x sp

typedef __bf16 bf16x8 __attribute__((ext_vector_type(8)));
typedef __bf16 bf16x4v __attribute__((ext_vector_type(4)));
typedef float  f32x4  __attribute__((ext_vector_type(4)));
using bf16 = __hip_bfloat16;

// ---------------------------------------------------------------------------
// LayerNorm: one wave per row of 512 f32, output bf16.
// ---------------------------------------------------------------------------
__global__ __launch_bounds__(256) void ln_kernel(
    const float* __restrict__ in, const float* __restrict__ gam,
    const float* __restrict__ bet, bf16* __restrict__ out)
{
    int wave = threadIdx.x >> 6, lane = threadIdx.x & 63;
    int row  = blockIdx.x * 4 + wave;
    const float* p = in + (size_t)row * D_ + lane * 8;
    float4 v0 = *(const float4*)p;
    float4 v1 = *(const float4*)(p + 4);
    float s  = v0.x + v0.y + v0.z + v0.w + v1.x + v1.y + v1.z + v1.w;
    float ss = v0.x*v0.x + v0.y*v0.y + v0.z*v0.z + v0.w*v0.w
             + v1.x*v1.x + v1.y*v1.y + v1.z*v1.z + v1.w*v1.w;
    for (int m = 1; m < 64; m <<= 1) {
        s  += __shfl_xor(s,  m, 64);
        ss += __shfl_xor(ss, m, 64);
    }
    float mu   = s * (1.f / D_);
    float var  = ss * (1.f / D_) - mu * mu;
    float rstd = rsqrtf(var + 1e-6f);
    int c = lane * 8;
    float4 g0 = *(const float4*)(gam + c), g1 = *(const float4*)(gam + c + 4);
    float4 b0 = *(const float4*)(bet + c), b1 = *(const float4*)(bet + c + 4);
    bf16* o = out + (size_t)row * D_ + c;
    o[0] = __float2bfloat16((v0.x - mu) * rstd * g0.x + b0.x);
    o[1] = __float2bfloat16((v0.y - mu) * rstd * g0.y + b0.y);
    o[2] = __float2bfloat16((v0.z - mu) * rstd * g0.z + b0.z);
    o[3] = __float2bfloat16((v0.w - mu) * rstd * g0.w + b0.w);
    o[4] = __float2bfloat16((v1.x - mu) * rstd * g1.x + b1.x);
    o[5] = __float2bfloat16((v1.y - mu) * rstd * g1.y + b1.y);
    o[6] = __float2bfloat16((v1.z - mu) * rstd * g1.z + b1.z);
    o[7] = __float2bfloat16((v1.w - mu) * rstd * g1.w + b1.w);
}

// ---------------------------------------------------------------------------
// Weight transpose + cast: W[K,N] f32 -> Wt[N,K] bf16.  block (32,8)
// ---------------------------------------------------------------------------
__global__ void wtrans_kernel(const float* __restrict__ W, bf16* __restrict__ Wt,
                              int K, int N)
{
    __shared__ float t[32][33];
    int tx = threadIdx.x, ty = threadIdx.y;
    int n0 = blockIdx.x * 32, k0 = blockIdx.y * 32;
    for (int j = 0; j < 32; j += 8)
        t[ty + j][tx] = W[(size_t)(k0 + ty + j) * N + n0 + tx];
    __syncthreads();
    for (int j = 0; j < 32; j += 8)
        Wt[(size_t)(n0 + ty + j) * K + k0 + tx] = __float2bfloat16(t[tx][ty + j]);
}

// Batched square (512x512) weight transpose: z picks which of the 4 weights.
__global__ void wtrans4_kernel(const float* __restrict__ Wq, const float* __restrict__ Wk,
                               const float* __restrict__ Wv, const float* __restrict__ Wo,
                               bf16* __restrict__ Wqt, bf16* __restrict__ Wkt,
                               bf16* __restrict__ Wvt, bf16* __restrict__ Wot)
{
    int z = blockIdx.z;
    const float* W = z == 0 ? Wq : (z == 1 ? Wk : (z == 2 ? Wv : Wo));
    bf16* Wt       = z == 0 ? Wqt : (z == 1 ? Wkt : (z == 2 ? Wvt : Wot));
    __shared__ float t[32][33];
    int tx = threadIdx.x, ty = threadIdx.y;
    int n0 = blockIdx.x * 32, k0 = blockIdx.y * 32;
    for (int j = 0; j < 32; j += 8)
        t[ty + j][tx] = W[(size_t)(k0 + ty + j) * D_ + n0 + tx];
    __syncthreads();
    for (int j = 0; j < 32; j += 8)
        Wt[(size_t)(n0 + ty + j) * D_ + k0 + tx] = __float2bfloat16(t[tx][ty + j]);
}

// ---------------------------------------------------------------------------
// V transpose per head: v[b*M+m][h*64+d] bf16 -> vt[(b*H+h)*64 + d][m] bf16
// ---------------------------------------------------------------------------
__global__ void vtrans_kernel(const bf16* __restrict__ v, bf16* __restrict__ vt)
{
    __shared__ bf16 t[32][33];
    int tx = threadIdx.x, ty = threadIdx.y;
    int bh = blockIdx.z, b = bh >> 3, h = bh & 7;
    int m0 = blockIdx.x * 32, d0 = blockIdx.y * 32;
    for (int j = 0; j < 32; j += 8)
        t[ty + j][tx] = v[(size_t)(b * M_ + m0 + ty + j) * D_ + h * DH_ + d0 + tx];
    __syncthreads();
    for (int j = 0; j < 32; j += 8)
        vt[((size_t)bh * DH_ + d0 + ty + j) * M_ + m0 + tx] = t[tx][ty + j];
}

// ---------------------------------------------------------------------------
// Generic GEMM (128x128 tile, 4 waves, BK=32) — used for MLP1 only now.
// ---------------------------------------------------------------------------
#define BM 128
#define BN 128
#define BK 32
#define LDK 40            // padded LDS row length in bf16 elems (80 B)

#define GEMM_BODY(Aptr, Btptr, KK, EPILOGUE)                                         \
    __shared__ bf16 As[BM * LDK];                                                    \
    __shared__ bf16 Bs[BN * LDK];                                                    \
    int t = threadIdx.x;                                                             \
    int lane = t & 63, wave = t >> 6;                                                \
    int wm = wave >> 1, wn = wave & 1;                                               \
    int r16 = lane & 15, g = lane >> 4;                                              \
    int m0 = blockIdx.x * BM, n0 = blockIdx.y * BN;                                  \
    f32x4 acc[4][4] = {};                                                            \
    for (int k0 = 0; k0 < (KK); k0 += BK) {                                          \
        __syncthreads();                                                             \
        for (int it = 0; it < 2; ++it) {                                             \
            int c = it * 256 + t;                                                    \
            int row = c >> 2, ko = (c & 3) * 8;                                      \
            uint4 dA = *(const uint4*)((Aptr)  + (size_t)(m0 + row) * (KK) + k0 + ko); \
            *(uint4*)((char*)As + row * (LDK * 2) + ko * 2) = dA;                    \
            uint4 dB = *(const uint4*)((Btptr) + (size_t)(n0 + row) * (KK) + k0 + ko); \
            *(uint4*)((char*)Bs + row * (LDK * 2) + ko * 2) = dB;                    \
        }                                                                            \
        __syncthreads();                                                             \
        bf16x8 af[4], bfr[4];                                                        \
        for (int i = 0; i < 4; ++i)                                                  \
            af[i]  = *(const bf16x8*)((char*)As + (wm * 64 + i * 16 + r16) * (LDK * 2) + g * 16); \
        for (int i = 0; i < 4; ++i)                                                  \
            bfr[i] = *(const bf16x8*)((char*)Bs + (wn * 64 + i * 16 + r16) * (LDK * 2) + g * 16); \
        for (int i = 0; i < 4; ++i)                                                  \
            for (int j = 0; j < 4; ++j)                                              \
                acc[i][j] = __builtin_amdgcn_mfma_f32_16x16x32_bf16(af[i], bfr[j], acc[i][j], 0, 0, 0); \
    }                                                                                \
    for (int i = 0; i < 4; ++i) {                                                    \
        int rb = m0 + wm * 64 + i * 16 + g * 4;                                      \
        for (int j = 0; j < 4; ++j) {                                                \
            int cb = n0 + wn * 64 + j * 16 + r16;                                    \
            float bia = bias[cb];                                                    \
            for (int e = 0; e < 4; ++e) {                                            \
                int rr = rb + e;                                                     \
                float val = acc[i][j][e] + bia;                                      \
                EPILOGUE                                                             \
            }                                                                        \
        }                                                                            \
    }

template<bool GELU, bool RESID, bool ROWMASK, bool OUTBF>
__global__ __launch_bounds__(256) void gemm_bt(
    const bf16* __restrict__ A, const bf16* __restrict__ Bt,
    const float* __restrict__ bias, const float* __restrict__ resid,
    const float* __restrict__ rowmask,
    bf16* __restrict__ outb, float* __restrict__ outf,
    int Mr, int Nn, int K)
{
    GEMM_BODY(A, Bt, K,
        if (GELU)    val = 0.5f * val * (1.f + erff(val * 0.70710678118654752f));
        if (RESID)   val += resid[(size_t)rr * Nn + cb];
        if (ROWMASK) val *= rowmask[rr];
        if (OUTBF)   outb[(size_t)rr * Nn + cb] = __float2bfloat16(val);
        else         outf[(size_t)rr * Nn + cb] = val;
    )
}

// ---------------------------------------------------------------------------
// 64x64-tile GEMM for N=512 outputs. 4 waves (2x2, each 32x32), BK=64,
// reg-staged double-buffered LDS, XOR-swizzled for conflict-free b128 reads.
// ---------------------------------------------------------------------------
template<bool RESID, bool ROWMASK, bool OUTBF>
__device__ __forceinline__ void gemm64_body(
    const bf16* __restrict__ A, const bf16* __restrict__ Bt,
    const float* __restrict__ bias, const float* __restrict__ resid,
    const float* __restrict__ rowmask,
    bf16* __restrict__ outb, float* __restrict__ outf,
    int Nn, int K)
{
    __shared__ __align__(16) char As[2][64 * 128];
    __shared__ __align__(16) char Bs[2][64 * 128];
    int t = threadIdx.x, lane = t & 63, wave = t >> 6;
    int wm = wave >> 1, wn = wave & 1;
    int r16 = lane & 15, g = lane >> 4;
    int m0 = blockIdx.x * 64, n0 = blockIdx.y * 64;

    const int sr0 = t >> 3, sr1 = sr0 + 32, sc = t & 7;
    const int wof0 = sr0 * 128 + ((sc ^ (sr0 & 7)) << 4);
    const int wof1 = sr1 * 128 + ((sc ^ (sr1 & 7)) << 4);
    const int rsw0 = ((g     ^ (r16 & 7)) << 4);   // ks=0 chunk
    const int rsw1 = (((4 + g) ^ (r16 & 7)) << 4); // ks=1 chunk

    uint4 a0, a1, b0, b1;
#define G64_LOAD(k0)                                                         \
    a0 = *(const uint4*)(A  + (size_t)(m0 + sr0) * K + (k0) + sc * 8);       \
    a1 = *(const uint4*)(A  + (size_t)(m0 + sr1) * K + (k0) + sc * 8);       \
    b0 = *(const uint4*)(Bt + (size_t)(n0 + sr0) * K + (k0) + sc * 8);       \
    b1 = *(const uint4*)(Bt + (size_t)(n0 + sr1) * K + (k0) + sc * 8);
#define G64_WRITE(buf)                                                       \
    *(uint4*)(As[buf] + wof0) = a0;  *(uint4*)(As[buf] + wof1) = a1;         \
    *(uint4*)(Bs[buf] + wof0) = b0;  *(uint4*)(Bs[buf] + wof1) = b1;

    f32x4 acc[2][2] = {};
    G64_LOAD(0)
    G64_WRITE(0)
    int cur = 0;
    const int nit = K >> 6;
    for (int it = 0; it < nit; ++it) {
        if (it + 1 < nit) { G64_LOAD((it + 1) << 6) }
        __syncthreads();
        bf16x8 af[2][2], bfr[2][2];
#pragma unroll
        for (int i = 0; i < 2; ++i) {
            af[i][0] = *(const bf16x8*)(As[cur] + (wm * 32 + i * 16 + r16) * 128 + rsw0);
            af[i][1] = *(const bf16x8*)(As[cur] + (wm * 32 + i * 16 + r16) * 128 + rsw1);
            bfr[i][0] = *(const bf16x8*)(Bs[cur] + (wn * 32 + i * 16 + r16) * 128 + rsw0);
            bfr[i][1] = *(const bf16x8*)(Bs[cur] + (wn * 32 + i * 16 + r16) * 128 + rsw1);
        }
        __builtin_amdgcn_s_setprio(1);
#pragma unroll
        for (int i = 0; i < 2; ++i)
#pragma unroll
            for (int j = 0; j < 2; ++j) {
                acc[i][j] = __builtin_amdgcn_mfma_f32_16x16x32_bf16(af[i][0], bfr[j][0], acc[i][j], 0, 0, 0);
                acc[i][j] = __builtin_amdgcn_mfma_f32_16x16x32_bf16(af[i][1], bfr[j][1], acc[i][j], 0, 0, 0);
            }
        __builtin_amdgcn_s_setprio(0);
        if (it + 1 < nit) { G64_WRITE(cur ^ 1) }
        cur ^= 1;
    }
#undef G64_LOAD
#undef G64_WRITE

#pragma unroll
    for (int i = 0; i < 2; ++i) {
        int rb = m0 + wm * 32 + i * 16 + g * 4;
#pragma unroll
        for (int j = 0; j < 2; ++j) {
            int cb = n0 + wn * 32 + j * 16 + r16;
            float bia = bias[cb];
#pragma unroll
            for (int e = 0; e < 4; ++e) {
                int rr = rb + e;
                float val = acc[i][j][e] + bia;
                if (RESID)   val += resid[(size_t)rr * Nn + cb];
                if (ROWMASK) val *= rowmask[rr];
                if (OUTBF)   outb[(size_t)rr * Nn + cb] = __float2bfloat16(val);
                else         outf[(size_t)rr * Nn + cb] = val;
            }
        }
    }
}

template<bool RESID, bool OUTBF>
__global__ __launch_bounds__(256) void gemm64(
    const bf16* __restrict__ A, const bf16* __restrict__ Bt,
    const float* __restrict__ bias, const float* __restrict__ resid,
    bf16* __restrict__ outb, float* __restrict__ outf, int Nn, int K)
{
    gemm64_body<RESID, false, OUTBF>(A, Bt, bias, resid, nullptr, outb, outf, Nn, K);
}

// Batched Q/K/V projection on the 64x64 tile: z selects Q, K, or V.
__global__ __launch_bounds__(256) void gemm64_qkv(
    const bf16* __restrict__ xn, const bf16* __restrict__ yn,
    const bf16* __restrict__ Wqt, const bf16* __restrict__ Wkt, const bf16* __restrict__ Wvt,
    const float* __restrict__ bq, const float* __restrict__ bk, const float* __restrict__ bv,
    const float* __restrict__ mask_x, const float* __restrict__ mask_y,
    bf16* __restrict__ qb, bf16* __restrict__ kb, bf16* __restrict__ vb)
{
    int z = blockIdx.z;
    const bf16* A        = z == 0 ? xn : yn;
    const bf16* Bt       = z == 0 ? Wqt : (z == 1 ? Wkt : Wvt);
    const float* bias    = z == 0 ? bq  : (z == 1 ? bk  : bv);
    const float* rowmask = z == 0 ? mask_x : mask_y;
    bf16* outb           = z == 0 ? qb  : (z == 1 ? kb  : vb);
    gemm64_body<false, true, true>(A, Bt, bias, nullptr, rowmask, outb, nullptr, D_, D_);
}

// ---------------------------------------------------------------------------
// Flash attention (swapped S^T = K*Q), LDS-staged double-buffered K/V with
// XOR swizzle, reg-staged. 1D grid ATT_GRID with XCD-chunked remap so blocks
// sharing a (bh,sp) K/V slice land on one XCD. 4 waves, 32 q-rows per wave.
// T13 defer-max (THR=8). bf16 numerator out + per-row (m,l) f32.
// ---------------------------------------------------------------------------
__global__ __launch_bounds__(256, 3) void attn_kernel(
    const bf16* __restrict__ q, const bf16* __restrict__ kk,
    const bf16* __restrict__ vt, bf16* __restrict__ num,
    float* __restrict__ ml)
{
    // XCD-chunked bijective remap (ATT_GRID % 8 == 0)
    int bid = blockIdx.x;
    int wg  = (bid & 7) * (ATT_GRID / 8) + (bid >> 3);
    int n0  = (wg & 15) * 128;
    int bh  = (wg >> 4) & 15;
    int sp  = wg >> 8;
    int b = bh >> 3, h = bh & 7;
    int t = threadIdx.x, lane = t & 63, wave = t >> 6;
    int ql = lane & 15, gg = lane >> 4;

    __shared__ __align__(16) char KsB[2][64 * 128];   // [key][d] swizzled
    __shared__ __align__(16) char VsB[2][64 * 128];   // [d][key] swizzled
    __shared__ __align__(16) bf16 plds[4][16][72];    // per-wave P tile [q][key]

    // Q fragments (B-operand), pre-scaled by 1/sqrt(dh) = 0.125 (exact)
    bf16x8 qf0[2], qf1[2];
    {
        int qr0 = b * N_ + n0 + wave * 32 + ql;
        for (int ks = 0; ks < 2; ++ks) {
            bf16x8 qv = *(const bf16x8*)(q + (size_t)qr0 * D_ + h * DH_ + ks * 32 + gg * 8);
            for (int j = 0; j < 8; ++j) qv[j] = (__bf16)((float)qv[j] * 0.125f);
            qf0[ks] = qv;
            bf16x8 qw = *(const bf16x8*)(q + (size_t)(qr0 + 16) * D_ + h * DH_ + ks * 32 + gg * 8);
            for (int j = 0; j < 8; ++j) qw[j] = (__bf16)((float)qw[j] * 0.125f);
            qf1[ks] = qw;
        }
    }

    f32x4 cacc0[4] = {}, cacc1[4] = {};
    float m0r = -1e30f, l0r = 0.f, m1r = -1e30f, l1r = 0.f;

    const bf16* kbase = kk + (size_t)(b * M_ + sp * KV_PER) * D_ + h * DH_;
    const bf16* vtb   = vt + (size_t)bh * DH_ * M_ + sp * KV_PER;

    const int k0r = t >> 3,          kc0 = t & 7;
    const int k1r = (t >> 3) + 32;
    const int wofs0 = k0r * 128 + ((kc0 ^ (k0r & 7)) << 4);
    const int wofs1 = k1r * 128 + ((kc0 ^ (k1r & 7)) << 4);
    const int rsw0 = ((gg     ^ (ql & 7)) << 4);
    const int rsw1 = (((4 + gg) ^ (ql & 7)) << 4);

#define STAGE_LOAD(tt)                                                              \
    kw0 = *(const uint4*)(kbase + (size_t)((tt) * 64 + k0r) * D_ + kc0 * 8);        \
    kw1 = *(const uint4*)(kbase + (size_t)((tt) * 64 + k1r) * D_ + kc0 * 8);        \
    vw0 = *(const uint4*)(vtb + (size_t)k0r * M_ + (tt) * 64 + kc0 * 8);            \
    vw1 = *(const uint4*)(vtb + (size_t)k1r * M_ + (tt) * 64 + kc0 * 8);

#define STAGE_WRITE(buf)                                                            \
    *(uint4*)(KsB[buf] + wofs0) = kw0;                                              \
    *(uint4*)(KsB[buf] + wofs1) = kw1;                                              \
    *(uint4*)(VsB[buf] + wofs0) = vw0;                                              \
    *(uint4*)(VsB[buf] + wofs1) = vw1;

#define SOFTMAX_PV(S, MR, LR, CACC)                                                 \
    {                                                                               \
        float tmax = fmaxf(                                                         \
            fmaxf(fmaxf(fmaxf(S[0][0], S[0][1]), fmaxf(S[0][2], S[0][3])),          \
                  fmaxf(fmaxf(S[1][0], S[1][1]), fmaxf(S[1][2], S[1][3]))),         \
            fmaxf(fmaxf(fmaxf(S[2][0], S[2][1]), fmaxf(S[2][2], S[2][3])),          \
                  fmaxf(fmaxf(S[3][0], S[3][1]), fmaxf(S[3][2], S[3][3]))));        \
        tmax = fmaxf(tmax, __shfl_xor(tmax, 16, 64));                               \
        tmax = fmaxf(tmax, __shfl_xor(tmax, 32, 64));                               \
        if (__any(tmax - MR > 8.f)) {      /* T13 defer-max, THR=8 */               \
            float mnew = fmaxf(MR, tmax);                                           \
            float scl  = __expf(MR - mnew);                                         \
            MR = mnew;                                                              \
            LR *= scl;                                                              \
            for (int df = 0; df < 4; ++df)                                          \
                for (int e = 0; e < 4; ++e) CACC[df][e] *= scl;                     \
        }                                                                           \
        float p[4][4]; float ps = 0.f;                                              \
        for (int nf = 0; nf < 4; ++nf)                                              \
            for (int e = 0; e < 4; ++e) { p[nf][e] = __expf(S[nf][e] - MR); ps += p[nf][e]; } \
        ps += __shfl_xor(ps, 16, 64);                                               \
        ps += __shfl_xor(ps, 32, 64);                                               \
        LR += ps;                                                                   \
        for (int nf = 0; nf < 4; ++nf) {                                            \
            bf16x4v w;                                                              \
            w[0] = (__bf16)p[nf][0]; w[1] = (__bf16)p[nf][1];                       \
            w[2] = (__bf16)p[nf][2]; w[3] = (__bf16)p[nf][3];                       \
            *(bf16x4v*)(&plds[wave][ql][nf * 16 + 4 * gg]) = w;                     \
        }                                                                           \
        __builtin_amdgcn_s_setprio(1);                                              \
        for (int ks = 0; ks < 2; ++ks) {                                            \
            bf16x8 pf = *(const bf16x8*)((const char*)&plds[wave][0][0]             \
                                         + ql * 144 + ks * 64 + gg * 16);           \
            for (int df = 0; df < 4; ++df)                                          \
                CACC[df] = __builtin_amdgcn_mfma_f32_16x16x32_bf16(                 \
                    vf[df * 2 + ks], pf, CACC[df], 0, 0, 0);                        \
        }                                                                           \
        __builtin_amdgcn_s_setprio(0);                                              \
    }

    uint4 kw0, kw1, vw0, vw1;
    STAGE_LOAD(0)
    STAGE_WRITE(0)
    int cur = 0;

    for (int tt = 0; tt < NT; ++tt) {
        if (tt + 1 < NT) { STAGE_LOAD(tt + 1) }
        __syncthreads();

        const char* Kb = KsB[cur];
        const char* Vb = VsB[cur];

        bf16x8 kf[8];
#pragma unroll
        for (int nf = 0; nf < 4; ++nf) {
            kf[nf * 2 + 0] = *(const bf16x8*)(Kb + (nf * 16 + ql) * 128 + rsw0);
            kf[nf * 2 + 1] = *(const bf16x8*)(Kb + (nf * 16 + ql) * 128 + rsw1);
        }

        f32x4 s0[4] = {}, s1[4] = {};
        __builtin_amdgcn_s_setprio(1);
#pragma unroll
        for (int nf = 0; nf < 4; ++nf) {
            s0[nf] = __builtin_amdgcn_mfma_f32_16x16x32_bf16(kf[nf * 2 + 0], qf0[0], s0[nf], 0, 0, 0);
            s0[nf] = __builtin_amdgcn_mfma_f32_16x16x32_bf16(kf[nf * 2 + 1], qf0[1], s0[nf], 0, 0, 0);
            s1[nf] = __builtin_amdgcn_mfma_f32_16x16x32_bf16(kf[nf * 2 + 0], qf1[0], s1[nf], 0, 0, 0);
            s1[nf] = __builtin_amdgcn_mfma_f32_16x16x32_bf16(kf[nf * 2 + 1], qf1[1], s1[nf], 0, 0, 0);
        }
        __builtin_amdgcn_s_setprio(0);

        bf16x8 vf[8];
#pragma unroll
        for (int df = 0; df < 4; ++df) {
            vf[df * 2 + 0] = *(const bf16x8*)(Vb + (df * 16 + ql) * 128 + rsw0);
            vf[df * 2 + 1] = *(const bf16x8*)(Vb + (df * 16 + ql) * 128 + rsw1);
        }

        SOFTMAX_PV(s0, m0r, l0r, cacc0)
        SOFTMAX_PV(s1, m1r, l1r, cacc1)

        if (tt + 1 < NT) { STAGE_WRITE(cur ^ 1) }
        cur ^= 1;
    }

    {
        int qr0 = b * N_ + n0 + wave * 32 + ql;
        bf16* nb0 = num + (size_t)sp * ROWS * D_ + (size_t)qr0 * D_ + h * DH_;
        bf16* nb1 = num + (size_t)sp * ROWS * D_ + (size_t)(qr0 + 16) * D_ + h * DH_;
#pragma unroll
        for (int df = 0; df < 4; ++df) {
            bf16x4v w0, w1;
#pragma unroll
            for (int e = 0; e < 4; ++e) {
                w0[e] = (__bf16)cacc0[df][e];
                w1[e] = (__bf16)cacc1[df][e];
            }
            *(bf16x4v*)(nb0 + df * 16 + 4 * gg) = w0;
            *(bf16x4v*)(nb1 + df * 16 + 4 * gg) = w1;
        }
        if (lane < 16) {
            size_t base = ((size_t)(sp * (B_ * H_) + bh) * N_ + (n0 + wave * 32 + ql)) * 2;
            ml[base] = m0r; ml[base + 1] = l0r;
            size_t base1 = ((size_t)(sp * (B_ * H_) + bh) * N_ + (n0 + wave * 32 + 16 + ql)) * 2;
            ml[base1] = m1r; ml[base1 + 1] = l1r;
        }
    }
#undef STAGE_LOAD
#undef STAGE_WRITE
#undef SOFTMAX_PV
}

// Combine the SPLIT partials (bf16 numerators) -> bf16 ctx
__global__ __launch_bounds__(256) void attn_combine(
    const bf16* __restrict__ num, const float* __restrict__ ml,
    bf16* __restrict__ ctx)
{
    int idx = blockIdx.x * 256 + threadIdx.x;
    int row = idx >> 7;              // 128 four-col chunks per row
    int c4  = (idx & 127) << 2;
    int b = row >> 11, n = row & (N_ - 1);
    int h = c4 >> 6;
    int bh = (b << 3) + h;
    float mv[SPLIT], lv[SPLIT];
#pragma unroll
    for (int sp = 0; sp < SPLIT; ++sp) {
        const float* mp = ml + ((size_t)(sp * (B_ * H_) + bh) * N_ + n) * 2;
        mv[sp] = mp[0]; lv[sp] = mp[1];
    }
    float mx = mv[0];
#pragma unroll
    for (int sp = 1; sp < SPLIT; ++sp) mx = fmaxf(mx, mv[sp]);
    float den = 0.f;
    float wsc[SPLIT];
#pragma unroll
    for (int sp = 0; sp < SPLIT; ++sp) {
        wsc[sp] = __expf(mv[sp] - mx);
        den += wsc[sp] * lv[sp];
    }
    float inv = 1.f / den;
    float ax = 0.f, ay = 0.f, az = 0.f, aw = 0.f;
#pragma unroll
    for (int sp = 0; sp < SPLIT; ++sp) {
        bf16x4v v = *(const bf16x4v*)(num + (size_t)sp * ROWS * D_ + (size_t)row * D_ + c4);
        ax += wsc[sp] * (float)v[0]; ay += wsc[sp] * (float)v[1];
        az += wsc[sp] * (float)v[2]; aw += wsc[sp] * (float)v[3];
    }
    bf16* o = ctx + (size_t)row * D_ + c4;
    o[0] = __float2bfloat16(ax * inv);
    o[1] = __float2bfloat16(ay * inv);
    o[2] = __float2bfloat16(az * inv);
    o[3] = __float2bfloat16(aw * inv);
}

// ---------------------------------------------------------------------------
extern "C" void kernel_launch(void* const* d_in, const int* in_sizes, int n_in,
                              void* d_out, int out_size, void* d_ws, size_t ws_size,
                              hipStream_t stream)
{
    const float* x      = (const float*)d_in[0];
    const float* y      = (const float*)d_in[1];
    const float* mask_x = (const float*)d_in[2];
    const float* mask_y = (const float*)d_in[3];
    const float* Wq = (const float*)d_in[4];  const float* bq = (const float*)d_in[5];
    const float* Wk = (const float*)d_in[6];  const float* bk = (const float*)d_in[7];
    const float* Wv = (const float*)d_in[8];  const float* bv = (const float*)d_in[9];
    const float* Wo = (const float*)d_in[10]; const float* bo = (const float*)d_in[11];
    const float* W1 = (const float*)d_in[12]; const float* b1 = (const float*)d_in[13];
    const float* W2 = (const float*)d_in[14]; const float* b2 = (const float*)d_in[15];
    const float* ln1g = (const float*)d_in[16]; const float* ln1b = (const float*)d_in[17];
    const float* ln2g = (const float*)d_in[18]; const float* ln2b = (const float*)d_in[19];

    char* ws = (char*)d_ws;
    const size_t SZA = (size_t)ROWS * D_ * 2;     // 4 MiB bf16 activation
    bf16* xn   = (bf16*)ws;            ws += SZA;
    bf16* yn   = (bf16*)ws;            ws += SZA;
    bf16* qb   = (bf16*)ws;            ws += SZA;
    bf16* kb   = (bf16*)ws;            ws += SZA;
    bf16* vb   = (bf16*)ws;            ws += SZA;
    bf16* vtb  = (bf16*)ws;            ws += SZA;
    bf16* ctxb = (bf16*)ws;            ws += SZA;
    bf16* xn2  = (bf16*)ws;            ws += SZA;
    bf16* hff  = (bf16*)ws;            ws += (size_t)ROWS * F_ * 2;
    float* x1  = (float*)ws;           ws += (size_t)ROWS * D_ * 4;
    bf16* Wqt = (bf16*)ws;             ws += (size_t)D_ * D_ * 2;
    bf16* Wkt = (bf16*)ws;             ws += (size_t)D_ * D_ * 2;
    bf16* Wvt = (bf16*)ws;             ws += (size_t)D_ * D_ * 2;
    bf16* Wot = (bf16*)ws;             ws += (size_t)D_ * D_ * 2;
    bf16* W1t = (bf16*)ws;             ws += (size_t)D_ * F_ * 2;
    bf16* W2t = (bf16*)ws;             ws += (size_t)F_ * D_ * 2;
    bf16* numb = (bf16*)ws;            ws += (size_t)SPLIT * ROWS * D_ * 2;
    float* mlb = (float*)ws;           ws += (size_t)SPLIT * B_ * H_ * N_ * 2 * 4;

    dim3 tb(32, 8);
    wtrans4_kernel<<<dim3(D_ / 32, D_ / 32, 4), tb, 0, stream>>>(
        Wq, Wk, Wv, Wo, Wqt, Wkt, Wvt, Wot);
    wtrans_kernel<<<dim3(F_ / 32, D_ / 32), tb, 0, stream>>>(W1, W1t, D_, F_);
    wtrans_kernel<<<dim3(D_ / 32, F_ / 32), tb, 0, stream>>>(W2, W2t, F_, D_);

    ln_kernel<<<ROWS / 4, 256, 0, stream>>>(x, ln1g, ln1b, xn);
    ln_kernel<<<ROWS / 4, 256, 0, stream>>>(y, ln1g, ln1b, yn);

    // Q/K/V projections, one batched launch (z = 0,1,2), 64x64 tiles
    gemm64_qkv<<<dim3(ROWS / 64, D_ / 64, 3), 256, 0, stream>>>(
        xn, yn, Wqt, Wkt, Wvt, bq, bk, bv, mask_x, mask_y, qb, kb, vb);

    vtrans_kernel<<<dim3(M_ / 32, DH_ / 32, B_ * H_), tb, 0, stream>>>(vb, vtb);

    attn_kernel<<<ATT_GRID, 256, 0, stream>>>(qb, kb, vtb, numb, mlb);
    attn_combine<<<(ROWS * D_ / 4) / 256, 256, 0, stream>>>(numb, mlb, ctxb);

    // out-proj + residual(x) -> x1 (f32), 64x64 tiles
    gemm64<true, false><<<dim3(ROWS / 64, D_ / 64), 256, 0, stream>>>(
        ctxb, Wot, bo, x, nullptr, x1, D_, D_);

    ln_kernel<<<ROWS / 4, 256, 0, stream>>>(x1, ln2g, ln2b, xn2);

    // MLP1 + GELU -> hff (bf16), 128x128 tiles (512 blocks)
    gemm_bt<true, false, false, true><<<dim3(ROWS / BM, F_ / BN), 256, 0, stream>>>(
        xn2, W1t, b1, nullptr, nullptr, hff, nullptr, ROWS, F_, D_);

    // MLP2 + residual(x1) -> d_out (f32), 64x64 tiles
    gemm64<true, false><<<dim3(ROWS / 64, D_ / 64), 256, 0, stream>>>(
        hff, W2t, b2, x1, nullptr, (float*)d_out, D_, F_);
}